// Round 1
// baseline (1299.275 us; speedup 1.0000x reference)
//
#include <hip/hip_runtime.h>
#include <cstdint>

// MultiheadRCDA: N=8, L=300, HH=WW=96, E=256, NH=8, HD=32
// Round 0: correct fp32 baseline.
//  - means commuted before k projections (linearity)
//  - fused bilinear attention: out[l,d] = sum_h wc[l,h] * sum_w wr[l,w] * V[h,w,d]

#define SCALE_Q 0.17677669529663687f  // 32^-0.5

// ---------------- mean kernels ----------------
__global__ __launch_bounds__(256) void mean_over_h_kernel(const float* __restrict__ in,
                                                          float* __restrict__ out) {
  int idx = blockIdx.x * 256 + threadIdx.x;  // [b][w][e], 8*96*256 = 196608
  int e = idx & 255;
  int bw = idx >> 8;
  int w = bw % 96;
  int b = bw / 96;
  const float* p = in + ((size_t)b * 9216 + w) * 256 + e;
  float s = 0.f;
#pragma unroll 8
  for (int h = 0; h < 96; ++h) s += p[(size_t)h * 24576];
  out[idx] = s * (1.f / 96.f);
}

__global__ __launch_bounds__(256) void mean_over_w_kernel(const float* __restrict__ in,
                                                          float* __restrict__ out) {
  int idx = blockIdx.x * 256 + threadIdx.x;  // [b][h][e]
  int e = idx & 255;
  int bh = idx >> 8;  // b*96+h
  const float* p = in + (size_t)bh * 24576 + e;
  float s = 0.f;
#pragma unroll 8
  for (int w = 0; w < 96; ++w) s += p[w * 256];
  out[idx] = s * (1.f / 96.f);
}

// ---------------- projection GEMM: C[M,256] = A[M,256] @ W[256,256]^T, +bias, *scale ----
// block: 256 threads, tile 64(m) x 256(n), K-steps of 16.
__global__ __launch_bounds__(256) void proj_gemm_kernel(
    const float* __restrict__ A, const float* __restrict__ W,
    const float* __restrict__ bias, float* __restrict__ C,
    int M, float scale, int permute) {
  __shared__ float As[64][17];
  __shared__ float Ws[256][17];
  int t = threadIdx.x;
  int m0 = blockIdx.x * 64;
  int ty = t >> 4;          // 0..15 -> m = m0 + ty*4 + i
  int tx = t & 15;          // n = j*16 + tx (conflict-free LDS read pattern)
  int lr = t >> 2;
  int lc = (t & 3) * 4;
  float acc[4][16];
#pragma unroll
  for (int i = 0; i < 4; ++i)
#pragma unroll
    for (int j = 0; j < 16; ++j) acc[i][j] = 0.f;

  for (int k0 = 0; k0 < 256; k0 += 16) {
    {
      int m = m0 + lr;
      float4 a = {0.f, 0.f, 0.f, 0.f};
      if (m < M) a = *(const float4*)(A + (size_t)m * 256 + k0 + lc);
      As[lr][lc] = a.x; As[lr][lc + 1] = a.y; As[lr][lc + 2] = a.z; As[lr][lc + 3] = a.w;
    }
#pragma unroll
    for (int rep = 0; rep < 4; ++rep) {
      int nrow = rep * 64 + lr;
      float4 wv = *(const float4*)(W + (size_t)nrow * 256 + k0 + lc);
      Ws[nrow][lc] = wv.x; Ws[nrow][lc + 1] = wv.y; Ws[nrow][lc + 2] = wv.z; Ws[nrow][lc + 3] = wv.w;
    }
    __syncthreads();
#pragma unroll
    for (int kk = 0; kk < 16; ++kk) {
      float a_[4], w_[16];
#pragma unroll
      for (int i = 0; i < 4; ++i) a_[i] = As[ty * 4 + i][kk];
#pragma unroll
      for (int j = 0; j < 16; ++j) w_[j] = Ws[j * 16 + tx][kk];
#pragma unroll
      for (int i = 0; i < 4; ++i)
#pragma unroll
        for (int j = 0; j < 16; ++j) acc[i][j] += a_[i] * w_[j];
    }
    __syncthreads();
  }
#pragma unroll
  for (int i = 0; i < 4; ++i) {
    int m = m0 + ty * 4 + i;
    if (m >= M) continue;
#pragma unroll
    for (int j = 0; j < 16; ++j) {
      int nn = j * 16 + tx;
      float val = (acc[i][j] + bias[nn]) * scale;
      size_t oidx;
      if (permute) {  // row m = b*300+l  ->  out[(l*8+b)*256 + n]
        int bb = m / 300, ll = m - bb * 300;
        oidx = ((size_t)ll * 8 + bb) * 256 + nn;
      } else {
        oidx = (size_t)m * 256 + nn;
      }
      C[oidx] = val;
    }
  }
}

// ---------------- scores + softmax ----------------
// grid (300, 8, 16): z = b + 8*kind. kind 0: row (qr,krp->wrow), 1: col (qc,kcp->wcol)
__global__ __launch_bounds__(128) void scores_softmax_kernel(
    const float* __restrict__ qr, const float* __restrict__ qc,
    const float* __restrict__ krp, const float* __restrict__ kcp,
    float* __restrict__ wrow, float* __restrict__ wcol) {
  int l = blockIdx.x, n = blockIdx.y, z = blockIdx.z;
  int b = z & 7, kind = z >> 3;
  const float* q = kind ? qc : qr;
  const float* k = kind ? kcp : krp;
  float* o = kind ? wcol : wrow;
  __shared__ float qs[32];
  __shared__ float red[128];
  int t = threadIdx.x;
  if (t < 32) qs[t] = q[((size_t)b * 300 + l) * 256 + n * 32 + t];
  __syncthreads();
  float s = -1e30f;
  if (t < 96) {
    const float* kp = k + ((size_t)b * 96 + t) * 256 + n * 32;
    float acc = 0.f;
#pragma unroll
    for (int d = 0; d < 32; ++d) acc += qs[d] * kp[d];
    s = acc;
  }
  red[t] = s;
  __syncthreads();
  for (int off = 64; off > 0; off >>= 1) {
    if (t < off) red[t] = fmaxf(red[t], red[t + off]);
    __syncthreads();
  }
  float m = red[0];
  __syncthreads();
  float e = (t < 96) ? __expf(s - m) : 0.f;
  red[t] = e;
  __syncthreads();
  for (int off = 64; off > 0; off >>= 1) {
    if (t < off) red[t] += red[t + off];
    __syncthreads();
  }
  float inv = 1.f / red[0];
  if (t < 96) o[(((size_t)b * 8 + n) * 300 + l) * 96 + t] = e * inv;
}

// ---------------- fused bilinear attention ----------------
// out[b,l,n*32+d] = sum_h wc[bn,l,h] * sum_w wr[bn,l,w] * v[b,h,w,n*32+d]
// grid (5, 8, 8) = (l-tile of 64, n, b); 256 threads; per-thread 2l x 4d.
#define LT 64
__global__ __launch_bounds__(256) void attn_kernel(
    const float* __restrict__ v, const float* __restrict__ wrow,
    const float* __restrict__ wcol, float* __restrict__ out) {
  int lt = blockIdx.x, n = blockIdx.y, b = blockIdx.z;
  int bn = b * 8 + n;
  int l0 = lt * LT;
  int nl = 300 - l0; if (nl > LT) nl = LT;
  __shared__ float wcT[96][LT];   // [h][ll]
  __shared__ float wrT[96][LT];   // [w][ll]
  __shared__ float Vs[96][32];    // [w][d] for current h
  int t = threadIdx.x;
  for (int f = t; f < 96 * LT; f += 256) {
    int ll = f & (LT - 1);
    int h = f >> 6;
    float cv = 0.f, rv = 0.f;
    if (ll < nl) {
      size_t base = ((size_t)bn * 300 + l0 + ll) * 96 + h;
      cv = wcol[base];
      rv = wrow[base];
    }
    wcT[h][ll] = cv;
    wrT[h][ll] = rv;
  }
  int tx = t & 7;    // d0 = tx*4
  int ty = t >> 3;   // ll0 = ty*2
  float acc[2][4] = {{0.f, 0.f, 0.f, 0.f}, {0.f, 0.f, 0.f, 0.f}};
  const float* vbase = v + (size_t)b * 9216 * 256 + n * 32;
  for (int h = 0; h < 96; ++h) {
    __syncthreads();  // also covers the wcT/wrT staging before h==0
    for (int f = t; f < 96 * 32; f += 256) {
      int w = f >> 5, d = f & 31;
      Vs[w][d] = vbase[((size_t)h * 96 + w) * 256 + d];
    }
    __syncthreads();
    float s[2][4] = {{0.f, 0.f, 0.f, 0.f}, {0.f, 0.f, 0.f, 0.f}};
#pragma unroll 8
    for (int w = 0; w < 96; ++w) {
      float2 r = *(const float2*)&wrT[w][ty * 2];
      float4 vv4 = *(const float4*)&Vs[w][tx * 4];
      s[0][0] += r.x * vv4.x; s[0][1] += r.x * vv4.y;
      s[0][2] += r.x * vv4.z; s[0][3] += r.x * vv4.w;
      s[1][0] += r.y * vv4.x; s[1][1] += r.y * vv4.y;
      s[1][2] += r.y * vv4.z; s[1][3] += r.y * vv4.w;
    }
    float2 c = *(const float2*)&wcT[h][ty * 2];
#pragma unroll
    for (int j = 0; j < 4; ++j) {
      acc[0][j] += c.x * s[0][j];
      acc[1][j] += c.y * s[1][j];
    }
  }
#pragma unroll
  for (int i = 0; i < 2; ++i) {
    int ll = ty * 2 + i;
    if (ll < nl) {
      float* po = out + ((size_t)b * 300 + l0 + ll) * 256 + n * 32 + tx * 4;
#pragma unroll
      for (int j = 0; j < 4; ++j) po[j] = acc[i][j];
    }
  }
}

// ---------------- launch ----------------
extern "C" void kernel_launch(void* const* d_in, const int* in_sizes, int n_in,
                              void* d_out, int out_size, void* d_ws, size_t ws_size,
                              hipStream_t stream) {
  const float* query_row = (const float*)d_in[0];
  const float* query_col = (const float*)d_in[1];
  const float* key_row   = (const float*)d_in[2];
  const float* key_col   = (const float*)d_in[3];
  const float* value     = (const float*)d_in[4];
  const float* W         = (const float*)d_in[5];  // (1280,256)
  const float* Bv        = (const float*)d_in[6];  // (1280,)
  const float* Wout      = (const float*)d_in[7];  // (256,256)
  const float* Bout      = (const float*)d_in[8];  // (256,)

  float* ws = (float*)d_ws;
  float* krm  = ws;                   // 8*96*256   = 196608
  float* kcm  = krm + 196608;         // 196608
  float* qr   = kcm + 196608;         // 8*300*256  = 614400
  float* qc   = qr + 614400;          // 614400
  float* krp  = qc + 614400;          // 196608
  float* kcp  = krp + 196608;         // 196608
  float* vv   = kcp + 196608;         // 8*96*96*256 = 18874368
  float* wrow = vv + 18874368;        // 8*8*300*96 = 1843200
  float* wcol = wrow + 1843200;       // 1843200
  float* ao   = wcol + 1843200;       // 614400
  // total: 25,190,400 floats = 100.8 MB of d_ws

  mean_over_h_kernel<<<768, 256, 0, stream>>>(key_row, krm);
  mean_over_w_kernel<<<768, 256, 0, stream>>>(key_col, kcm);
  proj_gemm_kernel<<<dim3(38, 1, 1), 256, 0, stream>>>(query_row, W,             Bv,        qr,  2400,  SCALE_Q, 0);
  proj_gemm_kernel<<<dim3(38, 1, 1), 256, 0, stream>>>(query_col, W + 65536,     Bv + 256,  qc,  2400,  SCALE_Q, 0);
  proj_gemm_kernel<<<dim3(12, 1, 1), 256, 0, stream>>>(krm,       W + 2 * 65536, Bv + 512,  krp, 768,   1.f, 0);
  proj_gemm_kernel<<<dim3(12, 1, 1), 256, 0, stream>>>(kcm,       W + 3 * 65536, Bv + 768,  kcp, 768,   1.f, 0);
  proj_gemm_kernel<<<dim3(1152, 1, 1), 256, 0, stream>>>(value,   W + 4 * 65536, Bv + 1024, vv,  73728, 1.f, 0);
  scores_softmax_kernel<<<dim3(300, 8, 16), 128, 0, stream>>>(qr, qc, krp, kcp, wrow, wcol);
  attn_kernel<<<dim3(5, 8, 8), 256, 0, stream>>>(vv, wrow, wcol, ao);
  proj_gemm_kernel<<<dim3(38, 1, 1), 256, 0, stream>>>(ao, Wout, Bout, (float*)d_out, 2400, 1.f, 1);
}

// Round 2
// 272.015 us; speedup vs baseline: 4.7765x; 4.7765x over previous
//
#include <hip/hip_runtime.h>
#include <cstdint>

// MultiheadRCDA: N=8, L=300, HH=WW=96, E=256, NH=8, HD=32
// Round 2: bf16 MFMA for all GEMM-shaped work; fp32 softmax/means/epilogues.

typedef __attribute__((ext_vector_type(8))) short short8v;  // bf16x8 MFMA frag
typedef __attribute__((ext_vector_type(4))) float f32x4;

#define SCALE_Q 0.17677669529663687f  // 32^-0.5

__device__ __forceinline__ unsigned short f2bf(float x) {
  unsigned int u = __builtin_bit_cast(unsigned int, x);
  u += 0x7FFFu + ((u >> 16) & 1u);
  return (unsigned short)(u >> 16);
}

// ---------------- weight fp32->bf16 ----------------
__global__ __launch_bounds__(256) void cvt_w_kernel(const float* __restrict__ w_in,
                                                    const float* __restrict__ w_out,
                                                    short* __restrict__ Wb) {
  int idx = blockIdx.x * 256 + threadIdx.x;  // 393216 total
  float v = (idx < 327680) ? w_in[idx] : w_out[idx - 327680];
  Wb[idx] = (short)f2bf(v);
}

// ---------------- mean kernels (fp32, HBM-bound) ----------------
__global__ __launch_bounds__(256) void mean_over_h_kernel(const float* __restrict__ in,
                                                          float* __restrict__ out) {
  int idx = blockIdx.x * 256 + threadIdx.x;  // [b][w][e]
  int e = idx & 255;
  int bw = idx >> 8;
  int w = bw % 96;
  int b = bw / 96;
  const float* p = in + ((size_t)b * 9216 + w) * 256 + e;
  float s = 0.f;
#pragma unroll 8
  for (int h = 0; h < 96; ++h) s += p[(size_t)h * 24576];
  out[idx] = s * (1.f / 96.f);
}

__global__ __launch_bounds__(256) void mean_over_w_kernel(const float* __restrict__ in,
                                                          float* __restrict__ out) {
  int idx = blockIdx.x * 256 + threadIdx.x;  // [b][h][e]
  int e = idx & 255;
  int bh = idx >> 8;
  const float* p = in + (size_t)bh * 24576 + e;
  float s = 0.f;
#pragma unroll 8
  for (int w = 0; w < 96; ++w) s += p[w * 256];
  out[idx] = s * (1.f / 96.f);
}

// ---------------- bf16 MFMA projection GEMM ----------------
// C[M,256] = A[M,256] @ Wb[256,256]^T (+bias)*scale
// block: 256 thr = 4 waves; tile 64m x 256n; wave owns 64 n-cols.
// mode 0: Cf[m][n] fp32     mode 1: Cf[(l*8+b)][n] fp32 (m=b*300+l)
// mode 2: Cb = vvT bf16 [bn][d(32)][hw(9216)]  (m = b*9216+hw, n_full = n*32+d)
__global__ __launch_bounds__(256) void gemm_proj(
    const float* __restrict__ A, const short* __restrict__ Wb,
    const float* __restrict__ bias, float* __restrict__ Cf,
    short* __restrict__ Cb, int M, float scale, int mode) {
  __shared__ short As[64 * 264];
  int t = threadIdx.x;
  int m0 = blockIdx.x * 64;
  int wave = t >> 6, lane = t & 63, r = lane & 15, g = lane >> 4;

  // stage A tile fp32->bf16
  {
    int row = t >> 2, c0 = (t & 3) * 64;
    const float* ap = A + (size_t)(m0 + row) * 256 + c0;
    bool valid = (m0 + row) < M;
    short* dst = &As[row * 264 + c0];
#pragma unroll
    for (int i = 0; i < 8; ++i) {
      short8v v = {};
      if (valid) {
        float4 fa = *(const float4*)(ap + i * 8);
        float4 fb = *(const float4*)(ap + i * 8 + 4);
        v[0] = (short)f2bf(fa.x); v[1] = (short)f2bf(fa.y);
        v[2] = (short)f2bf(fa.z); v[3] = (short)f2bf(fa.w);
        v[4] = (short)f2bf(fb.x); v[5] = (short)f2bf(fb.y);
        v[6] = (short)f2bf(fb.z); v[7] = (short)f2bf(fb.w);
      }
      *(short8v*)(dst + i * 8) = v;
    }
  }
  __syncthreads();

  f32x4 acc[4][4] = {};
  const short* wbase = Wb + (size_t)(wave * 64 + r) * 256;
#pragma unroll
  for (int ks = 0; ks < 8; ++ks) {
    short8v af[4], bf[4];
#pragma unroll
    for (int mf = 0; mf < 4; ++mf)
      af[mf] = *(const short8v*)&As[(mf * 16 + r) * 264 + ks * 32 + g * 8];
#pragma unroll
    for (int nf = 0; nf < 4; ++nf)
      bf[nf] = *(const short8v*)(wbase + nf * 16 * 256 + ks * 32 + g * 8);
#pragma unroll
    for (int mf = 0; mf < 4; ++mf)
#pragma unroll
      for (int nf = 0; nf < 4; ++nf)
        acc[mf][nf] = __builtin_amdgcn_mfma_f32_16x16x32_bf16(af[mf], bf[nf], acc[mf][nf], 0, 0, 0);
  }

  if (mode == 2) {
    // transpose through LDS so global writes are 128-B contiguous per thread
    __syncthreads();
#pragma unroll
    for (int mf = 0; mf < 4; ++mf)
#pragma unroll
      for (int nf = 0; nf < 4; ++nf) {
        int nn = wave * 64 + nf * 16 + r;
        float bval = bias[nn];
#pragma unroll
        for (int i = 0; i < 4; ++i)
          As[(mf * 16 + g * 4 + i) * 264 + nn] = (short)f2bf(acc[mf][nf][i] + bval);
      }
    __syncthreads();
    int d = t & 31, n = t >> 5;
    int b = m0 / 9216, hw0 = m0 % 9216;
    short* dst = Cb + (size_t)(b * 8 + n) * 294912 + (size_t)d * 9216 + hw0;
#pragma unroll
    for (int i8 = 0; i8 < 8; ++i8) {
      short8v v;
#pragma unroll
      for (int j = 0; j < 8; ++j) v[j] = As[(i8 * 8 + j) * 264 + t];
      *(short8v*)(dst + i8 * 8) = v;
    }
  } else {
#pragma unroll
    for (int mf = 0; mf < 4; ++mf)
#pragma unroll
      for (int nf = 0; nf < 4; ++nf) {
        int nn = wave * 64 + nf * 16 + r;
        float bval = bias[nn];
#pragma unroll
        for (int i = 0; i < 4; ++i) {
          int m = m0 + mf * 16 + g * 4 + i;
          if (m >= M) continue;
          float val = (acc[mf][nf][i] + bval) * scale;
          if (mode == 0) {
            Cf[(size_t)m * 256 + nn] = val;
          } else {
            int bb = m / 300, ll = m - bb * 300;
            Cf[((size_t)ll * 8 + bb) * 256 + nn] = val;
          }
        }
      }
  }
}

// ---------------- scores + softmax (fp32 compute) ----------------
// grid (320, 8, 16): z = b + 8*kind. kind 0 -> wrowB bf16 [bn][320][96]
//                                    kind 1 -> wcolT f32 [bn][96][320]
__global__ __launch_bounds__(128) void scores_softmax_kernel(
    const float* __restrict__ qr, const float* __restrict__ qc,
    const float* __restrict__ krp, const float* __restrict__ kcp,
    short* __restrict__ wrowB, float* __restrict__ wcolT) {
  int l = blockIdx.x, n = blockIdx.y, z = blockIdx.z;
  int b = z & 7, kind = z >> 3;
  int bn = b * 8 + n;
  int t = threadIdx.x;
  if (l >= 300) {  // zero-fill pad rows so MFMA reads deterministic zeros
    if (t < 96) {
      if (kind == 0) wrowB[((size_t)bn * 320 + l) * 96 + t] = 0;
      else wcolT[((size_t)bn * 96 + t) * 320 + l] = 0.f;
    }
    return;
  }
  const float* q = kind ? qc : qr;
  const float* k = kind ? kcp : krp;
  __shared__ float qs[32];
  __shared__ float red[128];
  if (t < 32) qs[t] = q[((size_t)b * 300 + l) * 256 + n * 32 + t];
  __syncthreads();
  float s = -1e30f;
  if (t < 96) {
    const float* kp = k + ((size_t)b * 96 + t) * 256 + n * 32;
    float acc = 0.f;
#pragma unroll
    for (int d = 0; d < 32; ++d) acc += qs[d] * kp[d];
    s = acc;
  }
  red[t] = s;
  __syncthreads();
  for (int off = 64; off > 0; off >>= 1) {
    if (t < off) red[t] = fmaxf(red[t], red[t + off]);
    __syncthreads();
  }
  float m = red[0];
  __syncthreads();
  float e = (t < 96) ? __expf(s - m) : 0.f;
  red[t] = e;
  __syncthreads();
  for (int off = 64; off > 0; off >>= 1) {
    if (t < off) red[t] += red[t + off];
    __syncthreads();
  }
  float inv = 1.f / red[0];
  if (t < 96) {
    float wv = e * inv;
    if (kind == 0) wrowB[((size_t)bn * 320 + l) * 96 + t] = (short)f2bf(wv);
    else wcolT[((size_t)bn * 96 + t) * 320 + l] = wv;
  }
}

// ---------------- fused bilinear attention (MFMA) ----------------
// out[l,d] = sum_h wc[l,h] * (sum_w wr[l,w] * V[h,w,d])
// grid (5,8,8) = (l-tile 64, n, b); 4 waves: df = wave&1 (d half), hh = wave>>1 (h half)
__global__ __launch_bounds__(256) void attn_kernel(
    const short* __restrict__ wrowB, const float* __restrict__ wcolT,
    const short* __restrict__ vvT, float* __restrict__ ao) {
  __shared__ f32x4 cmb[2][4][64];
  int lh = blockIdx.x, n = blockIdx.y, b = blockIdx.z;
  int bn = b * 8 + n;
  int t = threadIdx.x, wave = t >> 6, lane = t & 63;
  int df = wave & 1, hh = wave >> 1;
  int lbase = lh * 64;
  int r = lane & 15, g = lane >> 4;

  // A-frags (softmax row weights), loaded once, reused over all h
  short8v a[4][3];
  const short* wr = wrowB + (size_t)bn * 320 * 96;
#pragma unroll
  for (int lf = 0; lf < 4; ++lf)
#pragma unroll
    for (int ks = 0; ks < 3; ++ks)
      a[lf][ks] = *(const short8v*)(wr + (lbase + lf * 16 + r) * 96 + ks * 32 + g * 8);

  const short* vb = vvT + (size_t)bn * 294912 + (size_t)(df * 16 + r) * 9216 + (size_t)hh * 48 * 96;
  const float* wcb = wcolT + ((size_t)bn * 96 + hh * 48) * 320 + lbase + g * 4;

  f32x4 acc[4] = {};
  short8v b0[3], b1[3];
  f32x4 w0[4], w1[4];
#pragma unroll
  for (int ks = 0; ks < 3; ++ks) b0[ks] = *(const short8v*)(vb + ks * 32 + g * 8);
#pragma unroll
  for (int lf = 0; lf < 4; ++lf) w0[lf] = *(const f32x4*)(wcb + lf * 16);

  for (int h2 = 0; h2 < 24; ++h2) {
    int h = h2 * 2;
#pragma unroll
    for (int ks = 0; ks < 3; ++ks) b1[ks] = *(const short8v*)(vb + (h + 1) * 96 + ks * 32 + g * 8);
#pragma unroll
    for (int lf = 0; lf < 4; ++lf) w1[lf] = *(const f32x4*)(wcb + (h + 1) * 320 + lf * 16);
    {
      f32x4 R[4] = {};
#pragma unroll
      for (int ks = 0; ks < 3; ++ks)
#pragma unroll
        for (int lf = 0; lf < 4; ++lf)
          R[lf] = __builtin_amdgcn_mfma_f32_16x16x32_bf16(a[lf][ks], b0[ks], R[lf], 0, 0, 0);
#pragma unroll
      for (int lf = 0; lf < 4; ++lf) acc[lf] += w0[lf] * R[lf];
    }
    if (h2 < 23) {
#pragma unroll
      for (int ks = 0; ks < 3; ++ks) b0[ks] = *(const short8v*)(vb + (h + 2) * 96 + ks * 32 + g * 8);
#pragma unroll
      for (int lf = 0; lf < 4; ++lf) w0[lf] = *(const f32x4*)(wcb + (h + 2) * 320 + lf * 16);
    }
    {
      f32x4 R[4] = {};
#pragma unroll
      for (int ks = 0; ks < 3; ++ks)
#pragma unroll
        for (int lf = 0; lf < 4; ++lf)
          R[lf] = __builtin_amdgcn_mfma_f32_16x16x32_bf16(a[lf][ks], b1[ks], R[lf], 0, 0, 0);
#pragma unroll
      for (int lf = 0; lf < 4; ++lf) acc[lf] += w1[lf] * R[lf];
    }
  }

  if (hh == 1) {
#pragma unroll
    for (int lf = 0; lf < 4; ++lf) cmb[df][lf][lane] = acc[lf];
  }
  __syncthreads();
  if (hh == 0) {
#pragma unroll
    for (int lf = 0; lf < 4; ++lf) {
      f32x4 o = cmb[df][lf][lane];
#pragma unroll
      for (int i = 0; i < 4; ++i) {
        int l = lbase + lf * 16 + g * 4 + i;
        if (l < 300)
          ao[((size_t)b * 300 + l) * 256 + n * 32 + df * 16 + r] = acc[lf][i] + o[i];
      }
    }
  }
}

// ---------------- launch ----------------
extern "C" void kernel_launch(void* const* d_in, const int* in_sizes, int n_in,
                              void* d_out, int out_size, void* d_ws, size_t ws_size,
                              hipStream_t stream) {
  const float* query_row = (const float*)d_in[0];
  const float* query_col = (const float*)d_in[1];
  const float* key_row   = (const float*)d_in[2];
  const float* key_col   = (const float*)d_in[3];
  const float* value     = (const float*)d_in[4];
  const float* W         = (const float*)d_in[5];  // (1280,256)
  const float* Bv        = (const float*)d_in[6];  // (1280,)
  const float* Wout      = (const float*)d_in[7];  // (256,256)
  const float* Bout      = (const float*)d_in[8];  // (256,)

  float* ws = (float*)d_ws;
  float* krm   = ws;                  // 196608
  float* kcm   = krm + 196608;        // 196608
  float* qr    = kcm + 196608;        // 614400
  float* qc    = qr + 614400;         // 614400
  float* krp   = qc + 614400;         // 196608
  float* kcp   = krp + 196608;        // 196608
  float* ao    = kcp + 196608;        // 614400
  float* wcolT = ao + 614400;         // 64*96*320 = 1966080
  short* wrowB = (short*)(wcolT + 1966080);  // 64*320*96 = 1966080 shorts
  short* vvT   = wrowB + 1966080;            // 64*32*9216 = 18874368 shorts
  short* Wb    = vvT + 18874368;             // 393216 shorts
  // total ~60.9 MB

  cvt_w_kernel<<<1536, 256, 0, stream>>>(W, Wout, Wb);
  mean_over_h_kernel<<<768, 256, 0, stream>>>(key_row, krm);
  mean_over_w_kernel<<<768, 256, 0, stream>>>(key_col, kcm);
  gemm_proj<<<38, 256, 0, stream>>>(query_row, Wb,          Bv,        qr,  nullptr, 2400, SCALE_Q, 0);
  gemm_proj<<<38, 256, 0, stream>>>(query_col, Wb + 65536,  Bv + 256,  qc,  nullptr, 2400, SCALE_Q, 0);
  gemm_proj<<<12, 256, 0, stream>>>(krm,       Wb + 131072, Bv + 512,  krp, nullptr, 768,  1.f, 0);
  gemm_proj<<<12, 256, 0, stream>>>(kcm,       Wb + 196608, Bv + 768,  kcp, nullptr, 768,  1.f, 0);
  gemm_proj<<<1152, 256, 0, stream>>>(value,   Wb + 262144, Bv + 1024, nullptr, vvT, 73728, 1.f, 2);
  scores_softmax_kernel<<<dim3(320, 8, 16), 128, 0, stream>>>(qr, qc, krp, kcp, wrowB, wcolT);
  attn_kernel<<<dim3(5, 8, 8), 256, 0, stream>>>(wrowB, wcolT, vvT, ao);
  gemm_proj<<<38, 256, 0, stream>>>(ao, Wb + 327680, Bout, (float*)d_out, nullptr, 2400, 1.f, 1);
}

// Round 3
// 232.440 us; speedup vs baseline: 5.5897x; 1.1703x over previous
//
#include <hip/hip_runtime.h>
#include <cstdint>

// MultiheadRCDA: N=8, L=300, HH=WW=96, E=256, NH=8, HD=32
// Round 3: MFMA scores+softmax (in-register, shfl reductions), q/k emitted bf16.

typedef __attribute__((ext_vector_type(8))) short short8v;  // bf16x8 MFMA frag
typedef __attribute__((ext_vector_type(4))) float f32x4;

#define SCALE_Q 0.17677669529663687f  // 32^-0.5

__device__ __forceinline__ unsigned short f2bf(float x) {
  unsigned int u = __builtin_bit_cast(unsigned int, x);
  u += 0x7FFFu + ((u >> 16) & 1u);
  return (unsigned short)(u >> 16);
}

// ---------------- weight fp32->bf16 ----------------
__global__ __launch_bounds__(256) void cvt_w_kernel(const float* __restrict__ w_in,
                                                    const float* __restrict__ w_out,
                                                    short* __restrict__ Wb) {
  int idx = blockIdx.x * 256 + threadIdx.x;  // 393216 total
  float v = (idx < 327680) ? w_in[idx] : w_out[idx - 327680];
  Wb[idx] = (short)f2bf(v);
}

// ---------------- mean kernels (fp32, HBM-bound) ----------------
__global__ __launch_bounds__(256) void mean_over_h_kernel(const float* __restrict__ in,
                                                          float* __restrict__ out) {
  int idx = blockIdx.x * 256 + threadIdx.x;  // [b][w][e]
  int e = idx & 255;
  int bw = idx >> 8;
  int w = bw % 96;
  int b = bw / 96;
  const float* p = in + ((size_t)b * 9216 + w) * 256 + e;
  float s = 0.f;
#pragma unroll 8
  for (int h = 0; h < 96; ++h) s += p[(size_t)h * 24576];
  out[idx] = s * (1.f / 96.f);
}

__global__ __launch_bounds__(256) void mean_over_w_kernel(const float* __restrict__ in,
                                                          float* __restrict__ out) {
  int idx = blockIdx.x * 256 + threadIdx.x;  // [b][h][e]
  int e = idx & 255;
  int bh = idx >> 8;
  const float* p = in + (size_t)bh * 24576 + e;
  float s = 0.f;
#pragma unroll 8
  for (int w = 0; w < 96; ++w) s += p[w * 256];
  out[idx] = s * (1.f / 96.f);
}

// ---------------- bf16 MFMA projection GEMM ----------------
// C[M,256] = A[M,256] @ Wb[256,256]^T (+bias)*scale
// block: 256 thr = 4 waves; tile 64m x 256n; wave owns 64 n-cols.
// mode 0: Cf[m][n] fp32     mode 1: Cf[(l*8+b)][n] fp32 (m=b*300+l)
// mode 2: Cb = vvT bf16 [bn][d(32)][hw(9216)]  (m = b*9216+hw)
// mode 3: Cb[m][256] bf16 (scaled)
__global__ __launch_bounds__(256) void gemm_proj(
    const float* __restrict__ A, const short* __restrict__ Wb,
    const float* __restrict__ bias, float* __restrict__ Cf,
    short* __restrict__ Cb, int M, float scale, int mode) {
  __shared__ short As[64 * 264];
  int t = threadIdx.x;
  int m0 = blockIdx.x * 64;
  int wave = t >> 6, lane = t & 63, r = lane & 15, g = lane >> 4;

  // stage A tile fp32->bf16
  {
    int row = t >> 2, c0 = (t & 3) * 64;
    const float* ap = A + (size_t)(m0 + row) * 256 + c0;
    bool valid = (m0 + row) < M;
    short* dst = &As[row * 264 + c0];
#pragma unroll
    for (int i = 0; i < 8; ++i) {
      short8v v = {};
      if (valid) {
        float4 fa = *(const float4*)(ap + i * 8);
        float4 fb = *(const float4*)(ap + i * 8 + 4);
        v[0] = (short)f2bf(fa.x); v[1] = (short)f2bf(fa.y);
        v[2] = (short)f2bf(fa.z); v[3] = (short)f2bf(fa.w);
        v[4] = (short)f2bf(fb.x); v[5] = (short)f2bf(fb.y);
        v[6] = (short)f2bf(fb.z); v[7] = (short)f2bf(fb.w);
      }
      *(short8v*)(dst + i * 8) = v;
    }
  }
  __syncthreads();

  f32x4 acc[4][4] = {};
  const short* wbase = Wb + (size_t)(wave * 64 + r) * 256;
#pragma unroll
  for (int ks = 0; ks < 8; ++ks) {
    short8v af[4], bf[4];
#pragma unroll
    for (int mf = 0; mf < 4; ++mf)
      af[mf] = *(const short8v*)&As[(mf * 16 + r) * 264 + ks * 32 + g * 8];
#pragma unroll
    for (int nf = 0; nf < 4; ++nf)
      bf[nf] = *(const short8v*)(wbase + nf * 16 * 256 + ks * 32 + g * 8);
#pragma unroll
    for (int mf = 0; mf < 4; ++mf)
#pragma unroll
      for (int nf = 0; nf < 4; ++nf)
        acc[mf][nf] = __builtin_amdgcn_mfma_f32_16x16x32_bf16(af[mf], bf[nf], acc[mf][nf], 0, 0, 0);
  }

  if (mode == 2) {
    // transpose through LDS so global writes are 128-B contiguous per thread
    __syncthreads();
#pragma unroll
    for (int mf = 0; mf < 4; ++mf)
#pragma unroll
      for (int nf = 0; nf < 4; ++nf) {
        int nn = wave * 64 + nf * 16 + r;
        float bval = bias[nn];
#pragma unroll
        for (int i = 0; i < 4; ++i)
          As[(mf * 16 + g * 4 + i) * 264 + nn] = (short)f2bf(acc[mf][nf][i] + bval);
      }
    __syncthreads();
    int d = t & 31, n = t >> 5;
    int b = m0 / 9216, hw0 = m0 % 9216;
    short* dst = Cb + (size_t)(b * 8 + n) * 294912 + (size_t)d * 9216 + hw0;
#pragma unroll
    for (int i8 = 0; i8 < 8; ++i8) {
      short8v v;
#pragma unroll
      for (int j = 0; j < 8; ++j) v[j] = As[(i8 * 8 + j) * 264 + t];
      *(short8v*)(dst + i8 * 8) = v;
    }
  } else {
#pragma unroll
    for (int mf = 0; mf < 4; ++mf)
#pragma unroll
      for (int nf = 0; nf < 4; ++nf) {
        int nn = wave * 64 + nf * 16 + r;
        float bval = bias[nn];
#pragma unroll
        for (int i = 0; i < 4; ++i) {
          int m = m0 + mf * 16 + g * 4 + i;
          if (m >= M) continue;
          float val = (acc[mf][nf][i] + bval) * scale;
          if (mode == 0) {
            Cf[(size_t)m * 256 + nn] = val;
          } else if (mode == 1) {
            int bb = m / 300, ll = m - bb * 300;
            Cf[((size_t)ll * 8 + bb) * 256 + nn] = val;
          } else {  // mode 3
            Cb[(size_t)m * 256 + nn] = (short)f2bf(val);
          }
        }
      }
  }
}

// ---------------- scores + softmax v2: MFMA + in-register softmax ----------------
// grid (4, 64, 2) = (l-chunk of 80, bn, kind); 64 threads (1 wave).
// kind 0: (qrb,krb) -> wrowB bf16 [bn][320][96]
// kind 1: (qcb,kcb) -> wcolT f32 [bn][96][320]
__global__ __launch_bounds__(64) void scores_softmax_v2(
    const short* __restrict__ qrb, const short* __restrict__ qcb,
    const short* __restrict__ krb, const short* __restrict__ kcb,
    short* __restrict__ wrowB, float* __restrict__ wcolT) {
  int lchunk = blockIdx.x, bn = blockIdx.y, kind = blockIdx.z;
  int b = bn >> 3, n = bn & 7;
  int lane = threadIdx.x;
  int r = lane & 15, g = lane >> 4;
  const short* qb = kind ? qcb : qrb;
  const short* kb = kind ? kcb : krb;
  int l0 = lchunk * 80;

  short8v a[5], bfr[6];
#pragma unroll
  for (int lf = 0; lf < 5; ++lf) {
    int l = l0 + lf * 16 + r;
    if (l > 299) l = 299;  // clamp; pad rows zeroed at store
    a[lf] = *(const short8v*)(qb + ((size_t)b * 300 + l) * 256 + n * 32 + g * 8);
  }
#pragma unroll
  for (int f = 0; f < 6; ++f)
    bfr[f] = *(const short8v*)(kb + ((size_t)b * 96 + f * 16 + r) * 256 + n * 32 + g * 8);

  f32x4 c[5][6];
#pragma unroll
  for (int lf = 0; lf < 5; ++lf)
#pragma unroll
    for (int f = 0; f < 6; ++f) {
      f32x4 z = {};
      c[lf][f] = __builtin_amdgcn_mfma_f32_16x16x32_bf16(a[lf], bfr[f], z, 0, 0, 0);
    }

  // softmax over w (96 vals/row): in-lane across 6 frags, cross-lane over r (bits 0..3)
#pragma unroll
  for (int lf = 0; lf < 5; ++lf)
#pragma unroll
    for (int i = 0; i < 4; ++i) {
      float m = c[lf][0][i];
#pragma unroll
      for (int f = 1; f < 6; ++f) m = fmaxf(m, c[lf][f][i]);
#pragma unroll
      for (int mask = 1; mask <= 8; mask <<= 1) m = fmaxf(m, __shfl_xor(m, mask, 64));
      float e[6], s = 0.f;
#pragma unroll
      for (int f = 0; f < 6; ++f) { e[f] = __expf(c[lf][f][i] - m); s += e[f]; }
#pragma unroll
      for (int mask = 1; mask <= 8; mask <<= 1) s += __shfl_xor(s, mask, 64);
      float inv = 1.f / s;
#pragma unroll
      for (int f = 0; f < 6; ++f) c[lf][f][i] = e[f] * inv;
    }

  if (kind == 0) {
#pragma unroll
    for (int lf = 0; lf < 5; ++lf)
#pragma unroll
      for (int i = 0; i < 4; ++i) {
        int l = l0 + lf * 16 + g * 4 + i;
        bool ok = (l < 300);
#pragma unroll
        for (int f = 0; f < 6; ++f) {
          float wv = ok ? c[lf][f][i] : 0.f;
          wrowB[((size_t)bn * 320 + l) * 96 + f * 16 + r] = (short)f2bf(wv);
        }
      }
  } else {
#pragma unroll
    for (int lf = 0; lf < 5; ++lf)
#pragma unroll
      for (int f = 0; f < 6; ++f) {
        int l = l0 + lf * 16 + g * 4;
        f32x4 wv = c[lf][f];
#pragma unroll
        for (int i = 0; i < 4; ++i) if (l + i >= 300) wv[i] = 0.f;
        *(f32x4*)(wcolT + ((size_t)bn * 96 + f * 16 + r) * 320 + l) = wv;
      }
  }
}

// ---------------- fused bilinear attention (MFMA) ----------------
// out[l,d] = sum_h wc[l,h] * (sum_w wr[l,w] * V[h,w,d])
// grid (5,8,8) = (l-tile 64, n, b); 4 waves: df = wave&1 (d half), hh = wave>>1 (h half)
__global__ __launch_bounds__(256) void attn_kernel(
    const short* __restrict__ wrowB, const float* __restrict__ wcolT,
    const short* __restrict__ vvT, float* __restrict__ ao) {
  __shared__ f32x4 cmb[2][4][64];
  int lh = blockIdx.x, n = blockIdx.y, b = blockIdx.z;
  int bn = b * 8 + n;
  int t = threadIdx.x, wave = t >> 6, lane = t & 63;
  int df = wave & 1, hh = wave >> 1;
  int lbase = lh * 64;
  int r = lane & 15, g = lane >> 4;

  short8v a[4][3];
  const short* wr = wrowB + (size_t)bn * 320 * 96;
#pragma unroll
  for (int lf = 0; lf < 4; ++lf)
#pragma unroll
    for (int ks = 0; ks < 3; ++ks)
      a[lf][ks] = *(const short8v*)(wr + (lbase + lf * 16 + r) * 96 + ks * 32 + g * 8);

  const short* vb = vvT + (size_t)bn * 294912 + (size_t)(df * 16 + r) * 9216 + (size_t)hh * 48 * 96;
  const float* wcb = wcolT + ((size_t)bn * 96 + hh * 48) * 320 + lbase + g * 4;

  f32x4 acc[4] = {};
  short8v b0[3], b1[3];
  f32x4 w0[4], w1[4];
#pragma unroll
  for (int ks = 0; ks < 3; ++ks) b0[ks] = *(const short8v*)(vb + ks * 32 + g * 8);
#pragma unroll
  for (int lf = 0; lf < 4; ++lf) w0[lf] = *(const f32x4*)(wcb + lf * 16);

  for (int h2 = 0; h2 < 24; ++h2) {
    int h = h2 * 2;
#pragma unroll
    for (int ks = 0; ks < 3; ++ks) b1[ks] = *(const short8v*)(vb + (h + 1) * 96 + ks * 32 + g * 8);
#pragma unroll
    for (int lf = 0; lf < 4; ++lf) w1[lf] = *(const f32x4*)(wcb + (h + 1) * 320 + lf * 16);
    {
      f32x4 R[4] = {};
#pragma unroll
      for (int ks = 0; ks < 3; ++ks)
#pragma unroll
        for (int lf = 0; lf < 4; ++lf)
          R[lf] = __builtin_amdgcn_mfma_f32_16x16x32_bf16(a[lf][ks], b0[ks], R[lf], 0, 0, 0);
#pragma unroll
      for (int lf = 0; lf < 4; ++lf) acc[lf] += w0[lf] * R[lf];
    }
    if (h2 < 23) {
#pragma unroll
      for (int ks = 0; ks < 3; ++ks) b0[ks] = *(const short8v*)(vb + (h + 2) * 96 + ks * 32 + g * 8);
#pragma unroll
      for (int lf = 0; lf < 4; ++lf) w0[lf] = *(const f32x4*)(wcb + (h + 2) * 320 + lf * 16);
    }
    {
      f32x4 R[4] = {};
#pragma unroll
      for (int ks = 0; ks < 3; ++ks)
#pragma unroll
        for (int lf = 0; lf < 4; ++lf)
          R[lf] = __builtin_amdgcn_mfma_f32_16x16x32_bf16(a[lf][ks], b1[ks], R[lf], 0, 0, 0);
#pragma unroll
      for (int lf = 0; lf < 4; ++lf) acc[lf] += w1[lf] * R[lf];
    }
  }

  if (hh == 1) {
#pragma unroll
    for (int lf = 0; lf < 4; ++lf) cmb[df][lf][lane] = acc[lf];
  }
  __syncthreads();
  if (hh == 0) {
#pragma unroll
    for (int lf = 0; lf < 4; ++lf) {
      f32x4 o = cmb[df][lf][lane];
#pragma unroll
      for (int i = 0; i < 4; ++i) {
        int l = lbase + lf * 16 + g * 4 + i;
        if (l < 300)
          ao[((size_t)b * 300 + l) * 256 + n * 32 + df * 16 + r] = acc[lf][i] + o[i];
      }
    }
  }
}

// ---------------- launch ----------------
extern "C" void kernel_launch(void* const* d_in, const int* in_sizes, int n_in,
                              void* d_out, int out_size, void* d_ws, size_t ws_size,
                              hipStream_t stream) {
  const float* query_row = (const float*)d_in[0];
  const float* query_col = (const float*)d_in[1];
  const float* key_row   = (const float*)d_in[2];
  const float* key_col   = (const float*)d_in[3];
  const float* value     = (const float*)d_in[4];
  const float* W         = (const float*)d_in[5];  // (1280,256)
  const float* Bv        = (const float*)d_in[6];  // (1280,)
  const float* Wout      = (const float*)d_in[7];  // (256,256)
  const float* Bout      = (const float*)d_in[8];  // (256,)

  float* ws = (float*)d_ws;
  float* krm   = ws;                        // 196608 f
  float* kcm   = krm + 196608;              // 196608 f
  float* ao    = kcm + 196608;              // 614400 f
  float* wcolT = ao + 614400;               // 1966080 f
  short* qrb   = (short*)(wcolT + 1966080); // 614400 s
  short* qcb   = qrb + 614400;              // 614400 s
  short* krb   = qcb + 614400;              // 196608 s
  short* kcb   = krb + 196608;              // 196608 s
  short* wrowB = kcb + 196608;              // 1966080 s
  short* vvT   = wrowB + 1966080;           // 18874368 s
  short* Wb    = vvT + 18874368;            // 393216 s
  // total ~57.6 MB

  cvt_w_kernel<<<1536, 256, 0, stream>>>(W, Wout, Wb);
  mean_over_h_kernel<<<768, 256, 0, stream>>>(key_row, krm);
  mean_over_w_kernel<<<768, 256, 0, stream>>>(key_col, kcm);
  gemm_proj<<<38, 256, 0, stream>>>(query_row, Wb,          Bv,        nullptr, qrb, 2400, SCALE_Q, 3);
  gemm_proj<<<38, 256, 0, stream>>>(query_col, Wb + 65536,  Bv + 256,  nullptr, qcb, 2400, SCALE_Q, 3);
  gemm_proj<<<12, 256, 0, stream>>>(krm,       Wb + 131072, Bv + 512,  nullptr, krb, 768,  1.f, 3);
  gemm_proj<<<12, 256, 0, stream>>>(kcm,       Wb + 196608, Bv + 768,  nullptr, kcb, 768,  1.f, 3);
  gemm_proj<<<1152, 256, 0, stream>>>(value,   Wb + 262144, Bv + 1024, nullptr, vvT, 73728, 1.f, 2);
  scores_softmax_v2<<<dim3(4, 64, 2), 64, 0, stream>>>(qrb, qcb, krb, kcb, wrowB, wcolT);
  attn_kernel<<<dim3(5, 8, 8), 256, 0, stream>>>(wrowB, wcolT, vvT, ao);
  gemm_proj<<<38, 256, 0, stream>>>(ao, Wb + 327680, Bout, (float*)d_out, nullptr, 2400, 1.f, 1);
}

// Round 4
// 226.696 us; speedup vs baseline: 5.7313x; 1.0253x over previous
//
#include <hip/hip_runtime.h>
#include <cstdint>

// MultiheadRCDA: N=8, L=300, HH=WW=96, E=256, NH=8, HD=32
// Round 4: pipelined vproj (no tail, direct stores), float4 means, merged q/k
// projections, 8-wave attn.

typedef __attribute__((ext_vector_type(8))) short short8v;  // bf16x8 MFMA frag
typedef __attribute__((ext_vector_type(4))) short short4v;  // 8B packed bf16 store
typedef __attribute__((ext_vector_type(4))) float f32x4;

#define SCALE_Q 0.17677669529663687f  // 32^-0.5

__device__ __forceinline__ unsigned short f2bf(float x) {
  unsigned int u = __builtin_bit_cast(unsigned int, x);
  u += 0x7FFFu + ((u >> 16) & 1u);
  return (unsigned short)(u >> 16);
}

// ---------------- weight fp32->bf16 ----------------
__global__ __launch_bounds__(256) void cvt_w_kernel(const float* __restrict__ w_in,
                                                    const float* __restrict__ w_out,
                                                    short* __restrict__ Wb) {
  int idx = blockIdx.x * 256 + threadIdx.x;  // 393216 total
  float v = (idx < 327680) ? w_in[idx] : w_out[idx - 327680];
  Wb[idx] = (short)f2bf(v);
}

// ---------------- mean kernels (float4, HBM-bound) ----------------
__global__ __launch_bounds__(256) void mean_over_h_v2(const float* __restrict__ in,
                                                      float* __restrict__ out) {
  int idx = blockIdx.x * 256 + threadIdx.x;  // [b][w][e4] : 8*96*64 = 49152
  int e4 = idx & 63, bw = idx >> 6;
  int w = bw % 96, b = bw / 96;
  const float4* p = (const float4*)(in + ((size_t)b * 9216 + w) * 256) + e4;
  float4 s = {0.f, 0.f, 0.f, 0.f};
#pragma unroll 8
  for (int h = 0; h < 96; ++h) {
    float4 v = p[(size_t)h * 6144];
    s.x += v.x; s.y += v.y; s.z += v.z; s.w += v.w;
  }
  s.x *= (1.f / 96.f); s.y *= (1.f / 96.f); s.z *= (1.f / 96.f); s.w *= (1.f / 96.f);
  ((float4*)out)[idx] = s;
}

__global__ __launch_bounds__(256) void mean_over_w_v2(const float* __restrict__ in,
                                                      float* __restrict__ out) {
  int idx = blockIdx.x * 256 + threadIdx.x;  // [b][h][e4]
  int e4 = idx & 63, bh = idx >> 6;
  const float4* p = (const float4*)(in + (size_t)bh * 24576) + e4;
  float4 s = {0.f, 0.f, 0.f, 0.f};
#pragma unroll 8
  for (int w = 0; w < 96; ++w) {
    float4 v = p[(size_t)w * 64];
    s.x += v.x; s.y += v.y; s.z += v.z; s.w += v.w;
  }
  s.x *= (1.f / 96.f); s.y *= (1.f / 96.f); s.z *= (1.f / 96.f); s.w *= (1.f / 96.f);
  ((float4*)out)[idx] = s;
}

// ---------------- bf16 MFMA projection GEMM (q/k/out) ----------------
// blockIdx.y selects (A0,C0) vs (A1,C1) with W += y*65536, bias += y*256.
// mode 1: Cf[(l*8+b)][n] fp32 (m=b*300+l)   mode 3: Cb[m][256] bf16 (scaled)
__global__ __launch_bounds__(256) void gemm_proj(
    const float* __restrict__ A0, const float* __restrict__ A1,
    const short* __restrict__ Wb, const float* __restrict__ bias,
    float* __restrict__ Cf, short* __restrict__ Cb0, short* __restrict__ Cb1,
    int M, float scale, int mode) {
  __shared__ short As[64 * 264];
  int y = blockIdx.y;
  const float* A = y ? A1 : A0;
  short* Cb = y ? Cb1 : Cb0;
  const short* Wp = Wb + y * 65536;
  const float* bp = bias + y * 256;
  int t = threadIdx.x;
  int m0 = blockIdx.x * 64;
  int wave = t >> 6, lane = t & 63, r = lane & 15, g = lane >> 4;

  {
    int row = t >> 2, c0 = (t & 3) * 64;
    const float* ap = A + (size_t)(m0 + row) * 256 + c0;
    bool valid = (m0 + row) < M;
    short* dst = &As[row * 264 + c0];
#pragma unroll
    for (int i = 0; i < 8; ++i) {
      short8v v = {};
      if (valid) {
        float4 fa = *(const float4*)(ap + i * 8);
        float4 fb = *(const float4*)(ap + i * 8 + 4);
        v[0] = (short)f2bf(fa.x); v[1] = (short)f2bf(fa.y);
        v[2] = (short)f2bf(fa.z); v[3] = (short)f2bf(fa.w);
        v[4] = (short)f2bf(fb.x); v[5] = (short)f2bf(fb.y);
        v[6] = (short)f2bf(fb.z); v[7] = (short)f2bf(fb.w);
      }
      *(short8v*)(dst + i * 8) = v;
    }
  }
  __syncthreads();

  f32x4 acc[4][4] = {};
  const short* wbase = Wp + (size_t)(wave * 64 + r) * 256;
#pragma unroll
  for (int ks = 0; ks < 8; ++ks) {
    short8v af[4], bf[4];
#pragma unroll
    for (int mf = 0; mf < 4; ++mf)
      af[mf] = *(const short8v*)&As[(mf * 16 + r) * 264 + ks * 32 + g * 8];
#pragma unroll
    for (int nf = 0; nf < 4; ++nf)
      bf[nf] = *(const short8v*)(wbase + nf * 16 * 256 + ks * 32 + g * 8);
#pragma unroll
    for (int mf = 0; mf < 4; ++mf)
#pragma unroll
      for (int nf = 0; nf < 4; ++nf)
        acc[mf][nf] = __builtin_amdgcn_mfma_f32_16x16x32_bf16(af[mf], bf[nf], acc[mf][nf], 0, 0, 0);
  }

#pragma unroll
  for (int mf = 0; mf < 4; ++mf)
#pragma unroll
    for (int nf = 0; nf < 4; ++nf) {
      int nn = wave * 64 + nf * 16 + r;
      float bval = bp[nn];
#pragma unroll
      for (int i = 0; i < 4; ++i) {
        int m = m0 + mf * 16 + g * 4 + i;
        if (m >= M) continue;
        float val = (acc[mf][nf][i] + bval) * scale;
        if (mode == 1) {
          int bb = m / 300, ll = m - bb * 300;
          Cf[((size_t)ll * 8 + bb) * 256 + nn] = val;
        } else {  // mode 3
          Cb[(size_t)m * 256 + nn] = (short)f2bf(val);
        }
      }
    }
}

// ---------------- value projection (pipelined, direct vvT stores) ----------------
// vvT[bn][d(32)][hw(9216)] bf16.  grid 768 blocks x 3 tiles of 32 rows; 4 waves.
__global__ __launch_bounds__(256, 3) void vproj_kernel(
    const float* __restrict__ A, const short* __restrict__ Wb,
    const float* __restrict__ bias, short* __restrict__ vvT) {
  __shared__ short As[2][32 * 264];
  int t = threadIdx.x;
  int wave = t >> 6, lane = t & 63, r = lane & 15, g = lane >> 4;
  int row = t >> 3, c0 = (t & 7) * 32;
  int tile0 = blockIdx.x * 3;

  float bias_v[4];
#pragma unroll
  for (int nf = 0; nf < 4; ++nf) bias_v[nf] = bias[wave * 64 + nf * 16 + r];

  const short* wbase = Wb + (size_t)(wave * 64 + r) * 256;

  float4 ld[8];
  {
    const float* ap = A + ((size_t)tile0 * 32 + row) * 256 + c0;
#pragma unroll
    for (int j = 0; j < 8; ++j) ld[j] = *(const float4*)(ap + j * 4);
  }

  for (int tt = 0; tt < 3; ++tt) {
    int m0 = (tile0 + tt) * 32;
    // convert current tile to bf16, write LDS (2-way bank alias only)
    short* dst = &As[tt & 1][row * 264 + c0];
#pragma unroll
    for (int j = 0; j < 4; ++j) {
      float4 fa = ld[2 * j], fb = ld[2 * j + 1];
      short8v v;
      v[0] = (short)f2bf(fa.x); v[1] = (short)f2bf(fa.y);
      v[2] = (short)f2bf(fa.z); v[3] = (short)f2bf(fa.w);
      v[4] = (short)f2bf(fb.x); v[5] = (short)f2bf(fb.y);
      v[6] = (short)f2bf(fb.z); v[7] = (short)f2bf(fb.w);
      *(short8v*)(dst + j * 8) = v;
    }
    // issue next tile's loads now; they stay in flight under this tile's MFMAs
    if (tt < 2) {
      const float* ap = A + ((size_t)(tile0 + tt + 1) * 32 + row) * 256 + c0;
#pragma unroll
      for (int j = 0; j < 8; ++j) ld[j] = *(const float4*)(ap + j * 4);
    }
    __syncthreads();

    f32x4 acc[2][4] = {};
    const short* as_ = &As[tt & 1][0];
#pragma unroll
    for (int ks = 0; ks < 8; ++ks) {
      short8v af0 = *(const short8v*)(as_ + r * 264 + ks * 32 + g * 8);
      short8v af1 = *(const short8v*)(as_ + (16 + r) * 264 + ks * 32 + g * 8);
      short8v bf[4];
#pragma unroll
      for (int nf = 0; nf < 4; ++nf)
        bf[nf] = *(const short8v*)(wbase + nf * 16 * 256 + ks * 32 + g * 8);
#pragma unroll
      for (int nf = 0; nf < 4; ++nf) {
        acc[0][nf] = __builtin_amdgcn_mfma_f32_16x16x32_bf16(af0, bf[nf], acc[0][nf], 0, 0, 0);
        acc[1][nf] = __builtin_amdgcn_mfma_f32_16x16x32_bf16(af1, bf[nf], acc[1][nf], 0, 0, 0);
      }
    }
    // direct stores: lane's 4 acc elems = 4 consecutive hw at fixed d -> 8B store
    int b_ = m0 / 9216, hw0 = m0 - b_ * 9216;
#pragma unroll
    for (int mf = 0; mf < 2; ++mf)
#pragma unroll
      for (int nf = 0; nf < 4; ++nf) {
        f32x4 v = acc[mf][nf];
        float bb = bias_v[nf];
        short4v o;
        o[0] = (short)f2bf(v[0] + bb); o[1] = (short)f2bf(v[1] + bb);
        o[2] = (short)f2bf(v[2] + bb); o[3] = (short)f2bf(v[3] + bb);
        int d = (nf & 1) * 16 + r;
        int n_out = wave * 2 + (nf >> 1);
        *(short4v*)(vvT + (size_t)(b_ * 8 + n_out) * 294912 + (size_t)d * 9216 +
                    hw0 + mf * 16 + g * 4) = o;
      }
    // single barrier per iter is sufficient with double-buffered LDS
  }
}

// ---------------- scores + softmax: MFMA + in-register softmax ----------------
__global__ __launch_bounds__(64) void scores_softmax_v2(
    const short* __restrict__ qrb, const short* __restrict__ qcb,
    const short* __restrict__ krb, const short* __restrict__ kcb,
    short* __restrict__ wrowB, float* __restrict__ wcolT) {
  int lchunk = blockIdx.x, bn = blockIdx.y, kind = blockIdx.z;
  int b = bn >> 3, n = bn & 7;
  int lane = threadIdx.x;
  int r = lane & 15, g = lane >> 4;
  const short* qb = kind ? qcb : qrb;
  const short* kb = kind ? kcb : krb;
  int l0 = lchunk * 80;

  short8v a[5], bfr[6];
#pragma unroll
  for (int lf = 0; lf < 5; ++lf) {
    int l = l0 + lf * 16 + r;
    if (l > 299) l = 299;
    a[lf] = *(const short8v*)(qb + ((size_t)b * 300 + l) * 256 + n * 32 + g * 8);
  }
#pragma unroll
  for (int f = 0; f < 6; ++f)
    bfr[f] = *(const short8v*)(kb + ((size_t)b * 96 + f * 16 + r) * 256 + n * 32 + g * 8);

  f32x4 c[5][6];
#pragma unroll
  for (int lf = 0; lf < 5; ++lf)
#pragma unroll
    for (int f = 0; f < 6; ++f) {
      f32x4 z = {};
      c[lf][f] = __builtin_amdgcn_mfma_f32_16x16x32_bf16(a[lf], bfr[f], z, 0, 0, 0);
    }

#pragma unroll
  for (int lf = 0; lf < 5; ++lf)
#pragma unroll
    for (int i = 0; i < 4; ++i) {
      float m = c[lf][0][i];
#pragma unroll
      for (int f = 1; f < 6; ++f) m = fmaxf(m, c[lf][f][i]);
#pragma unroll
      for (int mask = 1; mask <= 8; mask <<= 1) m = fmaxf(m, __shfl_xor(m, mask, 64));
      float e[6], s = 0.f;
#pragma unroll
      for (int f = 0; f < 6; ++f) { e[f] = __expf(c[lf][f][i] - m); s += e[f]; }
#pragma unroll
      for (int mask = 1; mask <= 8; mask <<= 1) s += __shfl_xor(s, mask, 64);
      float inv = 1.f / s;
#pragma unroll
      for (int f = 0; f < 6; ++f) c[lf][f][i] = e[f] * inv;
    }

  if (kind == 0) {
#pragma unroll
    for (int lf = 0; lf < 5; ++lf)
#pragma unroll
      for (int i = 0; i < 4; ++i) {
        int l = l0 + lf * 16 + g * 4 + i;
        bool ok = (l < 300);
#pragma unroll
        for (int f = 0; f < 6; ++f) {
          float wv = ok ? c[lf][f][i] : 0.f;
          wrowB[((size_t)bn * 320 + l) * 96 + f * 16 + r] = (short)f2bf(wv);
        }
      }
  } else {
#pragma unroll
    for (int lf = 0; lf < 5; ++lf)
#pragma unroll
      for (int f = 0; f < 6; ++f) {
        int l = l0 + lf * 16 + g * 4;
        f32x4 wv = c[lf][f];
#pragma unroll
        for (int i = 0; i < 4; ++i) if (l + i >= 300) wv[i] = 0.f;
        *(f32x4*)(wcolT + ((size_t)bn * 96 + f * 16 + r) * 320 + l) = wv;
      }
  }
}

// ---------------- fused bilinear attention (MFMA, 8 waves) ----------------
// grid (5,8,8); 8 waves: df = wave&1 (d half), hh = wave>>1 (h quarter, 24 each)
__global__ __launch_bounds__(512) void attn_kernel(
    const short* __restrict__ wrowB, const float* __restrict__ wcolT,
    const short* __restrict__ vvT, float* __restrict__ ao) {
  __shared__ f32x4 cmb[3][2][4][64];
  int lh = blockIdx.x, n = blockIdx.y, b = blockIdx.z;
  int bn = b * 8 + n;
  int t = threadIdx.x, wave = t >> 6, lane = t & 63;
  int df = wave & 1, hh = wave >> 1;
  int lbase = lh * 64;
  int r = lane & 15, g = lane >> 4;

  short8v a[4][3];
  const short* wr = wrowB + (size_t)bn * 320 * 96;
#pragma unroll
  for (int lf = 0; lf < 4; ++lf)
#pragma unroll
    for (int ks = 0; ks < 3; ++ks)
      a[lf][ks] = *(const short8v*)(wr + (lbase + lf * 16 + r) * 96 + ks * 32 + g * 8);

  const short* vb = vvT + (size_t)bn * 294912 + (size_t)(df * 16 + r) * 9216 + hh * 24 * 96;
  const float* wcb = wcolT + ((size_t)bn * 96 + hh * 24) * 320 + lbase + g * 4;

  f32x4 acc[4] = {};
  short8v b0[3], b1[3];
  f32x4 w0[4], w1[4];
#pragma unroll
  for (int ks = 0; ks < 3; ++ks) b0[ks] = *(const short8v*)(vb + ks * 32 + g * 8);
#pragma unroll
  for (int lf = 0; lf < 4; ++lf) w0[lf] = *(const f32x4*)(wcb + lf * 16);

  for (int h2 = 0; h2 < 12; ++h2) {
    int h = h2 * 2;
#pragma unroll
    for (int ks = 0; ks < 3; ++ks) b1[ks] = *(const short8v*)(vb + (h + 1) * 96 + ks * 32 + g * 8);
#pragma unroll
    for (int lf = 0; lf < 4; ++lf) w1[lf] = *(const f32x4*)(wcb + (h + 1) * 320 + lf * 16);
    {
      f32x4 R[4] = {};
#pragma unroll
      for (int ks = 0; ks < 3; ++ks)
#pragma unroll
        for (int lf = 0; lf < 4; ++lf)
          R[lf] = __builtin_amdgcn_mfma_f32_16x16x32_bf16(a[lf][ks], b0[ks], R[lf], 0, 0, 0);
#pragma unroll
      for (int lf = 0; lf < 4; ++lf) acc[lf] += w0[lf] * R[lf];
    }
    if (h2 < 11) {
#pragma unroll
      for (int ks = 0; ks < 3; ++ks) b0[ks] = *(const short8v*)(vb + (h + 2) * 96 + ks * 32 + g * 8);
#pragma unroll
      for (int lf = 0; lf < 4; ++lf) w0[lf] = *(const f32x4*)(wcb + (h + 2) * 320 + lf * 16);
    }
    {
      f32x4 R[4] = {};
#pragma unroll
      for (int ks = 0; ks < 3; ++ks)
#pragma unroll
        for (int lf = 0; lf < 4; ++lf)
          R[lf] = __builtin_amdgcn_mfma_f32_16x16x32_bf16(a[lf][ks], b1[ks], R[lf], 0, 0, 0);
#pragma unroll
      for (int lf = 0; lf < 4; ++lf) acc[lf] += w1[lf] * R[lf];
    }
  }

  if (hh > 0) {
#pragma unroll
    for (int lf = 0; lf < 4; ++lf) cmb[hh - 1][df][lf][lane] = acc[lf];
  }
  __syncthreads();
  if (hh == 0) {
#pragma unroll
    for (int lf = 0; lf < 4; ++lf) {
      f32x4 o = acc[lf];
#pragma unroll
      for (int q = 0; q < 3; ++q) o += cmb[q][df][lf][lane];
#pragma unroll
      for (int i = 0; i < 4; ++i) {
        int l = lbase + lf * 16 + g * 4 + i;
        if (l < 300)
          ao[((size_t)b * 300 + l) * 256 + n * 32 + df * 16 + r] = o[i];
      }
    }
  }
}

// ---------------- launch ----------------
extern "C" void kernel_launch(void* const* d_in, const int* in_sizes, int n_in,
                              void* d_out, int out_size, void* d_ws, size_t ws_size,
                              hipStream_t stream) {
  const float* query_row = (const float*)d_in[0];
  const float* query_col = (const float*)d_in[1];
  const float* key_row   = (const float*)d_in[2];
  const float* key_col   = (const float*)d_in[3];
  const float* value     = (const float*)d_in[4];
  const float* W         = (const float*)d_in[5];  // (1280,256)
  const float* Bv        = (const float*)d_in[6];  // (1280,)
  const float* Wout      = (const float*)d_in[7];  // (256,256)
  const float* Bout      = (const float*)d_in[8];  // (256,)

  float* ws = (float*)d_ws;
  float* krm   = ws;                        // 196608 f
  float* kcm   = krm + 196608;              // 196608 f
  float* ao    = kcm + 196608;              // 614400 f
  float* wcolT = ao + 614400;               // 1966080 f
  short* qrb   = (short*)(wcolT + 1966080); // 614400 s
  short* qcb   = qrb + 614400;              // 614400 s
  short* krb   = qcb + 614400;              // 196608 s
  short* kcb   = krb + 196608;              // 196608 s
  short* wrowB = kcb + 196608;              // 1966080 s
  short* vvT   = wrowB + 1966080;           // 18874368 s
  short* Wb    = vvT + 18874368;            // 393216 s

  cvt_w_kernel<<<1536, 256, 0, stream>>>(W, Wout, Wb);
  mean_over_h_v2<<<192, 256, 0, stream>>>(key_row, krm);
  mean_over_w_v2<<<192, 256, 0, stream>>>(key_col, kcm);
  gemm_proj<<<dim3(38, 2), 256, 0, stream>>>(query_row, query_col, Wb, Bv,
                                             nullptr, qrb, qcb, 2400, SCALE_Q, 3);
  gemm_proj<<<dim3(12, 2), 256, 0, stream>>>(krm, kcm, Wb + 131072, Bv + 512,
                                             nullptr, krb, kcb, 768, 1.f, 3);
  vproj_kernel<<<768, 256, 0, stream>>>(value, Wb + 262144, Bv + 1024, vvT);
  scores_softmax_v2<<<dim3(4, 64, 2), 64, 0, stream>>>(qrb, qcb, krb, kcb, wrowB, wcolT);
  attn_kernel<<<dim3(5, 8, 8), 512, 0, stream>>>(wrowB, wcolT, vvT, ao);
  gemm_proj<<<dim3(38, 1), 256, 0, stream>>>(ao, nullptr, Wb + 327680, Bout,
                                             (float*)d_out, nullptr, nullptr, 2400, 1.f, 1);
}

// Round 5
// 203.133 us; speedup vs baseline: 6.3962x; 1.1160x over previous
//
#include <hip/hip_runtime.h>
#include <cstdint>

// MultiheadRCDA: N=8, L=300, HH=WW=96, E=256, NH=8, HD=32
// Round 5: vproj rebuilt — one 32-row tile per block, 4 blocks/CU, LDS
// transpose epilogue for full-line 64B stores (kills RMW amplification).

typedef __attribute__((ext_vector_type(8))) short short8v;  // bf16x8 MFMA frag
typedef __attribute__((ext_vector_type(4))) short short4v;  // 8B packed bf16
typedef __attribute__((ext_vector_type(4))) float f32x4;

#define SCALE_Q 0.17677669529663687f  // 32^-0.5

__device__ __forceinline__ unsigned short f2bf(float x) {
  unsigned int u = __builtin_bit_cast(unsigned int, x);
  u += 0x7FFFu + ((u >> 16) & 1u);
  return (unsigned short)(u >> 16);
}

// ---------------- weight fp32->bf16 ----------------
__global__ __launch_bounds__(256) void cvt_w_kernel(const float* __restrict__ w_in,
                                                    const float* __restrict__ w_out,
                                                    short* __restrict__ Wb) {
  int idx = blockIdx.x * 256 + threadIdx.x;  // 393216 total
  float v = (idx < 327680) ? w_in[idx] : w_out[idx - 327680];
  Wb[idx] = (short)f2bf(v);
}

// ---------------- mean kernels (float4, HBM-bound) ----------------
__global__ __launch_bounds__(256) void mean_over_h_v2(const float* __restrict__ in,
                                                      float* __restrict__ out) {
  int idx = blockIdx.x * 256 + threadIdx.x;  // [b][w][e4]
  int e4 = idx & 63, bw = idx >> 6;
  int w = bw % 96, b = bw / 96;
  const float4* p = (const float4*)(in + ((size_t)b * 9216 + w) * 256) + e4;
  float4 s = {0.f, 0.f, 0.f, 0.f};
#pragma unroll 8
  for (int h = 0; h < 96; ++h) {
    float4 v = p[(size_t)h * 6144];
    s.x += v.x; s.y += v.y; s.z += v.z; s.w += v.w;
  }
  s.x *= (1.f / 96.f); s.y *= (1.f / 96.f); s.z *= (1.f / 96.f); s.w *= (1.f / 96.f);
  ((float4*)out)[idx] = s;
}

__global__ __launch_bounds__(256) void mean_over_w_v2(const float* __restrict__ in,
                                                      float* __restrict__ out) {
  int idx = blockIdx.x * 256 + threadIdx.x;  // [b][h][e4]
  int e4 = idx & 63, bh = idx >> 6;
  const float4* p = (const float4*)(in + (size_t)bh * 24576) + e4;
  float4 s = {0.f, 0.f, 0.f, 0.f};
#pragma unroll 8
  for (int w = 0; w < 96; ++w) {
    float4 v = p[(size_t)w * 64];
    s.x += v.x; s.y += v.y; s.z += v.z; s.w += v.w;
  }
  s.x *= (1.f / 96.f); s.y *= (1.f / 96.f); s.z *= (1.f / 96.f); s.w *= (1.f / 96.f);
  ((float4*)out)[idx] = s;
}

// ---------------- bf16 MFMA projection GEMM (q/k/out) ----------------
// blockIdx.y selects (A0,C0) vs (A1,C1) with W += y*65536, bias += y*256.
// mode 1: Cf[(l*8+b)][n] fp32 (m=b*300+l)   mode 3: Cb[m][256] bf16 (scaled)
__global__ __launch_bounds__(256) void gemm_proj(
    const float* __restrict__ A0, const float* __restrict__ A1,
    const short* __restrict__ Wb, const float* __restrict__ bias,
    float* __restrict__ Cf, short* __restrict__ Cb0, short* __restrict__ Cb1,
    int M, float scale, int mode) {
  __shared__ short As[64 * 264];
  int y = blockIdx.y;
  const float* A = y ? A1 : A0;
  short* Cb = y ? Cb1 : Cb0;
  const short* Wp = Wb + y * 65536;
  const float* bp = bias + y * 256;
  int t = threadIdx.x;
  int m0 = blockIdx.x * 64;
  int wave = t >> 6, lane = t & 63, r = lane & 15, g = lane >> 4;

  {
    int row = t >> 2, c0 = (t & 3) * 64;
    const float* ap = A + (size_t)(m0 + row) * 256 + c0;
    bool valid = (m0 + row) < M;
    short* dst = &As[row * 264 + c0];
#pragma unroll
    for (int i = 0; i < 8; ++i) {
      short8v v = {};
      if (valid) {
        float4 fa = *(const float4*)(ap + i * 8);
        float4 fb = *(const float4*)(ap + i * 8 + 4);
        v[0] = (short)f2bf(fa.x); v[1] = (short)f2bf(fa.y);
        v[2] = (short)f2bf(fa.z); v[3] = (short)f2bf(fa.w);
        v[4] = (short)f2bf(fb.x); v[5] = (short)f2bf(fb.y);
        v[6] = (short)f2bf(fb.z); v[7] = (short)f2bf(fb.w);
      }
      *(short8v*)(dst + i * 8) = v;
    }
  }
  __syncthreads();

  f32x4 acc[4][4] = {};
  const short* wbase = Wp + (size_t)(wave * 64 + r) * 256;
#pragma unroll
  for (int ks = 0; ks < 8; ++ks) {
    short8v af[4], bf[4];
#pragma unroll
    for (int mf = 0; mf < 4; ++mf)
      af[mf] = *(const short8v*)&As[(mf * 16 + r) * 264 + ks * 32 + g * 8];
#pragma unroll
    for (int nf = 0; nf < 4; ++nf)
      bf[nf] = *(const short8v*)(wbase + nf * 16 * 256 + ks * 32 + g * 8);
#pragma unroll
    for (int mf = 0; mf < 4; ++mf)
#pragma unroll
      for (int nf = 0; nf < 4; ++nf)
        acc[mf][nf] = __builtin_amdgcn_mfma_f32_16x16x32_bf16(af[mf], bf[nf], acc[mf][nf], 0, 0, 0);
  }

#pragma unroll
  for (int mf = 0; mf < 4; ++mf)
#pragma unroll
    for (int nf = 0; nf < 4; ++nf) {
      int nn = wave * 64 + nf * 16 + r;
      float bval = bp[nn];
#pragma unroll
      for (int i = 0; i < 4; ++i) {
        int m = m0 + mf * 16 + g * 4 + i;
        if (m >= M) continue;
        float val = (acc[mf][nf][i] + bval) * scale;
        if (mode == 1) {
          int bb = m / 300, ll = m - bb * 300;
          Cf[((size_t)ll * 8 + bb) * 256 + nn] = val;
        } else {  // mode 3
          Cb[(size_t)m * 256 + nn] = (short)f2bf(val);
        }
      }
    }
}

// ---------------- value projection v2 ----------------
// vvT[bn][d(32)][hw(9216)] bf16.  One 32-row tile per block, grid 2304.
// LDS transpose epilogue -> each thread stores one 64B-aligned 64B run.
__global__ __launch_bounds__(256, 4) void vproj_kernel(
    const float* __restrict__ A, const short* __restrict__ Wb,
    const float* __restrict__ bias, short* __restrict__ vvT) {
  __shared__ short As[32 * 264];
  __shared__ short Ts[256 * 36];
  int t = threadIdx.x;
  int wave = t >> 6, lane = t & 63, r = lane & 15, g = lane >> 4;
  int m0 = blockIdx.x * 32;

  // stage A tile (32x256 fp32 -> bf16); 8 independent float4 loads in flight
  {
    int row = t >> 3, c0 = (t & 7) * 32;
    const float* ap = A + ((size_t)m0 + row) * 256 + c0;
    float4 ld[8];
#pragma unroll
    for (int j = 0; j < 8; ++j) ld[j] = *(const float4*)(ap + j * 4);
    short* dst = &As[row * 264 + c0];
#pragma unroll
    for (int j = 0; j < 4; ++j) {
      float4 fa = ld[2 * j], fb = ld[2 * j + 1];
      short8v v;
      v[0] = (short)f2bf(fa.x); v[1] = (short)f2bf(fa.y);
      v[2] = (short)f2bf(fa.z); v[3] = (short)f2bf(fa.w);
      v[4] = (short)f2bf(fb.x); v[5] = (short)f2bf(fb.y);
      v[6] = (short)f2bf(fb.z); v[7] = (short)f2bf(fb.w);
      *(short8v*)(dst + j * 8) = v;
    }
  }
  __syncthreads();

  f32x4 acc[2][4] = {};
  const short* wbase = Wb + (size_t)(wave * 64 + r) * 256;
#pragma unroll
  for (int ks = 0; ks < 8; ++ks) {
    short8v af0 = *(const short8v*)&As[r * 264 + ks * 32 + g * 8];
    short8v af1 = *(const short8v*)&As[(16 + r) * 264 + ks * 32 + g * 8];
    short8v bf[4];
#pragma unroll
    for (int nf = 0; nf < 4; ++nf)
      bf[nf] = *(const short8v*)(wbase + nf * 16 * 256 + ks * 32 + g * 8);
#pragma unroll
    for (int nf = 0; nf < 4; ++nf) {
      acc[0][nf] = __builtin_amdgcn_mfma_f32_16x16x32_bf16(af0, bf[nf], acc[0][nf], 0, 0, 0);
      acc[1][nf] = __builtin_amdgcn_mfma_f32_16x16x32_bf16(af1, bf[nf], acc[1][nf], 0, 0, 0);
    }
  }

  // bias + transpose through LDS (stride 36 shorts: 8B-aligned, ~4-way max)
#pragma unroll
  for (int nf = 0; nf < 4; ++nf) {
    int nn = wave * 64 + nf * 16 + r;
    float bval = bias[nn];
#pragma unroll
    for (int mf = 0; mf < 2; ++mf) {
      short4v o;
      o[0] = (short)f2bf(acc[mf][nf][0] + bval);
      o[1] = (short)f2bf(acc[mf][nf][1] + bval);
      o[2] = (short)f2bf(acc[mf][nf][2] + bval);
      o[3] = (short)f2bf(acc[mf][nf][3] + bval);
      *(short4v*)&Ts[nn * 36 + mf * 16 + g * 4] = o;
    }
  }
  __syncthreads();

  // thread t owns output channel nn=t: 32 consecutive hw = 64B full-line store
  int b_ = m0 / 9216, hw0 = m0 - b_ * 9216;
  short* gdst = vvT + (size_t)(b_ * 8 + (t >> 5)) * 294912 + (size_t)(t & 31) * 9216 + hw0;
#pragma unroll
  for (int j = 0; j < 4; ++j) {
    short4v lo = *(const short4v*)&Ts[t * 36 + j * 8];
    short4v hi = *(const short4v*)&Ts[t * 36 + j * 8 + 4];
    short8v v;
    v[0] = lo[0]; v[1] = lo[1]; v[2] = lo[2]; v[3] = lo[3];
    v[4] = hi[0]; v[5] = hi[1]; v[6] = hi[2]; v[7] = hi[3];
    *(short8v*)(gdst + j * 8) = v;
  }
}

// ---------------- scores + softmax: MFMA + in-register softmax ----------------
__global__ __launch_bounds__(64) void scores_softmax_v2(
    const short* __restrict__ qrb, const short* __restrict__ qcb,
    const short* __restrict__ krb, const short* __restrict__ kcb,
    short* __restrict__ wrowB, float* __restrict__ wcolT) {
  int lchunk = blockIdx.x, bn = blockIdx.y, kind = blockIdx.z;
  int b = bn >> 3, n = bn & 7;
  int lane = threadIdx.x;
  int r = lane & 15, g = lane >> 4;
  const short* qb = kind ? qcb : qrb;
  const short* kb = kind ? kcb : krb;
  int l0 = lchunk * 80;

  short8v a[5], bfr[6];
#pragma unroll
  for (int lf = 0; lf < 5; ++lf) {
    int l = l0 + lf * 16 + r;
    if (l > 299) l = 299;
    a[lf] = *(const short8v*)(qb + ((size_t)b * 300 + l) * 256 + n * 32 + g * 8);
  }
#pragma unroll
  for (int f = 0; f < 6; ++f)
    bfr[f] = *(const short8v*)(kb + ((size_t)b * 96 + f * 16 + r) * 256 + n * 32 + g * 8);

  f32x4 c[5][6];
#pragma unroll
  for (int lf = 0; lf < 5; ++lf)
#pragma unroll
    for (int f = 0; f < 6; ++f) {
      f32x4 z = {};
      c[lf][f] = __builtin_amdgcn_mfma_f32_16x16x32_bf16(a[lf], bfr[f], z, 0, 0, 0);
    }

#pragma unroll
  for (int lf = 0; lf < 5; ++lf)
#pragma unroll
    for (int i = 0; i < 4; ++i) {
      float m = c[lf][0][i];
#pragma unroll
      for (int f = 1; f < 6; ++f) m = fmaxf(m, c[lf][f][i]);
#pragma unroll
      for (int mask = 1; mask <= 8; mask <<= 1) m = fmaxf(m, __shfl_xor(m, mask, 64));
      float e[6], s = 0.f;
#pragma unroll
      for (int f = 0; f < 6; ++f) { e[f] = __expf(c[lf][f][i] - m); s += e[f]; }
#pragma unroll
      for (int mask = 1; mask <= 8; mask <<= 1) s += __shfl_xor(s, mask, 64);
      float inv = 1.f / s;
#pragma unroll
      for (int f = 0; f < 6; ++f) c[lf][f][i] = e[f] * inv;
    }

  if (kind == 0) {
#pragma unroll
    for (int lf = 0; lf < 5; ++lf)
#pragma unroll
      for (int i = 0; i < 4; ++i) {
        int l = l0 + lf * 16 + g * 4 + i;
        bool ok = (l < 300);
#pragma unroll
        for (int f = 0; f < 6; ++f) {
          float wv = ok ? c[lf][f][i] : 0.f;
          wrowB[((size_t)bn * 320 + l) * 96 + f * 16 + r] = (short)f2bf(wv);
        }
      }
  } else {
#pragma unroll
    for (int lf = 0; lf < 5; ++lf)
#pragma unroll
      for (int f = 0; f < 6; ++f) {
        int l = l0 + lf * 16 + g * 4;
        f32x4 wv = c[lf][f];
#pragma unroll
        for (int i = 0; i < 4; ++i) if (l + i >= 300) wv[i] = 0.f;
        *(f32x4*)(wcolT + ((size_t)bn * 96 + f * 16 + r) * 320 + l) = wv;
      }
  }
}

// ---------------- fused bilinear attention (MFMA, 8 waves) ----------------
// grid (5,8,8); 8 waves: df = wave&1 (d half), hh = wave>>1 (h quarter, 24 each)
__global__ __launch_bounds__(512) void attn_kernel(
    const short* __restrict__ wrowB, const float* __restrict__ wcolT,
    const short* __restrict__ vvT, float* __restrict__ ao) {
  __shared__ f32x4 cmb[3][2][4][64];
  int lh = blockIdx.x, n = blockIdx.y, b = blockIdx.z;
  int bn = b * 8 + n;
  int t = threadIdx.x, wave = t >> 6, lane = t & 63;
  int df = wave & 1, hh = wave >> 1;
  int lbase = lh * 64;
  int r = lane & 15, g = lane >> 4;

  short8v a[4][3];
  const short* wr = wrowB + (size_t)bn * 320 * 96;
#pragma unroll
  for (int lf = 0; lf < 4; ++lf)
#pragma unroll
    for (int ks = 0; ks < 3; ++ks)
      a[lf][ks] = *(const short8v*)(wr + (lbase + lf * 16 + r) * 96 + ks * 32 + g * 8);

  const short* vb = vvT + (size_t)bn * 294912 + (size_t)(df * 16 + r) * 9216 + hh * 24 * 96;
  const float* wcb = wcolT + ((size_t)bn * 96 + hh * 24) * 320 + lbase + g * 4;

  f32x4 acc[4] = {};
  short8v b0[3], b1[3];
  f32x4 w0[4], w1[4];
#pragma unroll
  for (int ks = 0; ks < 3; ++ks) b0[ks] = *(const short8v*)(vb + ks * 32 + g * 8);
#pragma unroll
  for (int lf = 0; lf < 4; ++lf) w0[lf] = *(const f32x4*)(wcb + lf * 16);

  for (int h2 = 0; h2 < 12; ++h2) {
    int h = h2 * 2;
#pragma unroll
    for (int ks = 0; ks < 3; ++ks) b1[ks] = *(const short8v*)(vb + (h + 1) * 96 + ks * 32 + g * 8);
#pragma unroll
    for (int lf = 0; lf < 4; ++lf) w1[lf] = *(const f32x4*)(wcb + (h + 1) * 320 + lf * 16);
    {
      f32x4 R[4] = {};
#pragma unroll
      for (int ks = 0; ks < 3; ++ks)
#pragma unroll
        for (int lf = 0; lf < 4; ++lf)
          R[lf] = __builtin_amdgcn_mfma_f32_16x16x32_bf16(a[lf][ks], b0[ks], R[lf], 0, 0, 0);
#pragma unroll
      for (int lf = 0; lf < 4; ++lf) acc[lf] += w0[lf] * R[lf];
    }
    if (h2 < 11) {
#pragma unroll
      for (int ks = 0; ks < 3; ++ks) b0[ks] = *(const short8v*)(vb + (h + 2) * 96 + ks * 32 + g * 8);
#pragma unroll
      for (int lf = 0; lf < 4; ++lf) w0[lf] = *(const f32x4*)(wcb + (h + 2) * 320 + lf * 16);
    }
    {
      f32x4 R[4] = {};
#pragma unroll
      for (int ks = 0; ks < 3; ++ks)
#pragma unroll
        for (int lf = 0; lf < 4; ++lf)
          R[lf] = __builtin_amdgcn_mfma_f32_16x16x32_bf16(a[lf][ks], b1[ks], R[lf], 0, 0, 0);
#pragma unroll
      for (int lf = 0; lf < 4; ++lf) acc[lf] += w1[lf] * R[lf];
    }
  }

  if (hh > 0) {
#pragma unroll
    for (int lf = 0; lf < 4; ++lf) cmb[hh - 1][df][lf][lane] = acc[lf];
  }
  __syncthreads();
  if (hh == 0) {
#pragma unroll
    for (int lf = 0; lf < 4; ++lf) {
      f32x4 o = acc[lf];
#pragma unroll
      for (int q = 0; q < 3; ++q) o += cmb[q][df][lf][lane];
#pragma unroll
      for (int i = 0; i < 4; ++i) {
        int l = lbase + lf * 16 + g * 4 + i;
        if (l < 300)
          ao[((size_t)b * 300 + l) * 256 + n * 32 + df * 16 + r] = o[i];
      }
    }
  }
}

// ---------------- launch ----------------
extern "C" void kernel_launch(void* const* d_in, const int* in_sizes, int n_in,
                              void* d_out, int out_size, void* d_ws, size_t ws_size,
                              hipStream_t stream) {
  const float* query_row = (const float*)d_in[0];
  const float* query_col = (const float*)d_in[1];
  const float* key_row   = (const float*)d_in[2];
  const float* key_col   = (const float*)d_in[3];
  const float* value     = (const float*)d_in[4];
  const float* W         = (const float*)d_in[5];  // (1280,256)
  const float* Bv        = (const float*)d_in[6];  // (1280,)
  const float* Wout      = (const float*)d_in[7];  // (256,256)
  const float* Bout      = (const float*)d_in[8];  // (256,)

  float* ws = (float*)d_ws;
  float* krm   = ws;                        // 196608 f
  float* kcm   = krm + 196608;              // 196608 f
  float* ao    = kcm + 196608;              // 614400 f
  float* wcolT = ao + 614400;               // 1966080 f
  short* qrb   = (short*)(wcolT + 1966080); // 614400 s
  short* qcb   = qrb + 614400;              // 614400 s
  short* krb   = qcb + 614400;              // 196608 s
  short* kcb   = krb + 196608;              // 196608 s
  short* wrowB = kcb + 196608;              // 1966080 s
  short* vvT   = wrowB + 1966080;           // 18874368 s
  short* Wb    = vvT + 18874368;            // 393216 s

  cvt_w_kernel<<<1536, 256, 0, stream>>>(W, Wout, Wb);
  mean_over_h_v2<<<192, 256, 0, stream>>>(key_row, krm);
  mean_over_w_v2<<<192, 256, 0, stream>>>(key_col, kcm);
  gemm_proj<<<dim3(38, 2), 256, 0, stream>>>(query_row, query_col, Wb, Bv,
                                             nullptr, qrb, qcb, 2400, SCALE_Q, 3);
  gemm_proj<<<dim3(12, 2), 256, 0, stream>>>(krm, kcm, Wb + 131072, Bv + 512,
                                             nullptr, krb, kcb, 768, 1.f, 3);
  vproj_kernel<<<2304, 256, 0, stream>>>(value, Wb + 262144, Bv + 1024, vvT);
  scores_softmax_v2<<<dim3(4, 64, 2), 64, 0, stream>>>(qrb, qcb, krb, kcb, wrowB, wcolT);
  attn_kernel<<<dim3(5, 8, 8), 512, 0, stream>>>(wrowB, wcolT, vvT, ao);
  gemm_proj<<<dim3(38, 1), 256, 0, stream>>>(ao, nullptr, Wb + 327680, Bout,
                                             (float*)d_out, nullptr, nullptr, 2400, 1.f, 1);
}

// Round 6
// 179.538 us; speedup vs baseline: 7.2368x; 1.1314x over previous
//
#include <hip/hip_runtime.h>
#include <cstdint>

// MultiheadRCDA: N=8, L=300, HH=WW=96, E=256, NH=8, HD=32
// Round 6: vproj = depth-2 prefetch pipeline + per-wave transpose epilogue
// (clean 64B stores). gemm_proj BM=32 for 2x parallelism on small projections.

typedef __attribute__((ext_vector_type(8))) short short8v;  // bf16x8 MFMA frag
typedef __attribute__((ext_vector_type(4))) short short4v;  // 8B packed bf16
typedef __attribute__((ext_vector_type(4))) float f32x4;

#define SCALE_Q 0.17677669529663687f  // 32^-0.5

__device__ __forceinline__ unsigned short f2bf(float x) {
  unsigned int u = __builtin_bit_cast(unsigned int, x);
  u += 0x7FFFu + ((u >> 16) & 1u);
  return (unsigned short)(u >> 16);
}

__device__ __forceinline__ short8v pack8(const float4& fa, const float4& fb) {
  short8v v;
  v[0] = (short)f2bf(fa.x); v[1] = (short)f2bf(fa.y);
  v[2] = (short)f2bf(fa.z); v[3] = (short)f2bf(fa.w);
  v[4] = (short)f2bf(fb.x); v[5] = (short)f2bf(fb.y);
  v[6] = (short)f2bf(fb.z); v[7] = (short)f2bf(fb.w);
  return v;
}

// ---------------- weight fp32->bf16 ----------------
__global__ __launch_bounds__(256) void cvt_w_kernel(const float* __restrict__ w_in,
                                                    const float* __restrict__ w_out,
                                                    short* __restrict__ Wb) {
  int idx = blockIdx.x * 256 + threadIdx.x;  // 393216 total
  float v = (idx < 327680) ? w_in[idx] : w_out[idx - 327680];
  Wb[idx] = (short)f2bf(v);
}

// ---------------- mean kernels (float4, HBM-bound) ----------------
__global__ __launch_bounds__(256) void mean_over_h_v2(const float* __restrict__ in,
                                                      float* __restrict__ out) {
  int idx = blockIdx.x * 256 + threadIdx.x;  // [b][w][e4]
  int e4 = idx & 63, bw = idx >> 6;
  int w = bw % 96, b = bw / 96;
  const float4* p = (const float4*)(in + ((size_t)b * 9216 + w) * 256) + e4;
  float4 s = {0.f, 0.f, 0.f, 0.f};
#pragma unroll 8
  for (int h = 0; h < 96; ++h) {
    float4 v = p[(size_t)h * 6144];
    s.x += v.x; s.y += v.y; s.z += v.z; s.w += v.w;
  }
  s.x *= (1.f / 96.f); s.y *= (1.f / 96.f); s.z *= (1.f / 96.f); s.w *= (1.f / 96.f);
  ((float4*)out)[idx] = s;
}

__global__ __launch_bounds__(256) void mean_over_w_v2(const float* __restrict__ in,
                                                      float* __restrict__ out) {
  int idx = blockIdx.x * 256 + threadIdx.x;  // [b][h][e4]
  int e4 = idx & 63, bh = idx >> 6;
  const float4* p = (const float4*)(in + (size_t)bh * 24576) + e4;
  float4 s = {0.f, 0.f, 0.f, 0.f};
#pragma unroll 8
  for (int w = 0; w < 96; ++w) {
    float4 v = p[(size_t)w * 64];
    s.x += v.x; s.y += v.y; s.z += v.z; s.w += v.w;
  }
  s.x *= (1.f / 96.f); s.y *= (1.f / 96.f); s.z *= (1.f / 96.f); s.w *= (1.f / 96.f);
  ((float4*)out)[idx] = s;
}

// ---------------- bf16 MFMA projection GEMM (q/k/out), BM=32 ----------------
// C[M,256] = A[M,256] @ Wb[256,256]^T (+bias)*scale.  M % 32 == 0.
// blockIdx.y selects (A0,C0) vs (A1,C1) with W += y*65536, bias += y*256.
// mode 1: Cf[(l*8+b)][n] fp32 (m=b*300+l)   mode 3: Cb[m][256] bf16 (scaled)
__global__ __launch_bounds__(256) void gemm_proj(
    const float* __restrict__ A0, const float* __restrict__ A1,
    const short* __restrict__ Wb, const float* __restrict__ bias,
    float* __restrict__ Cf, short* __restrict__ Cb0, short* __restrict__ Cb1,
    float scale, int mode) {
  __shared__ short As[32 * 264];
  int y = blockIdx.y;
  const float* A = y ? A1 : A0;
  short* Cb = y ? Cb1 : Cb0;
  const short* Wp = Wb + y * 65536;
  const float* bp = bias + y * 256;
  int t = threadIdx.x;
  int m0 = blockIdx.x * 32;
  int wave = t >> 6, lane = t & 63, r = lane & 15, g = lane >> 4;

  {
    int row = t >> 3, c0 = (t & 7) * 32;
    const float* ap = A + ((size_t)m0 + row) * 256 + c0;
    float4 ld[8];
#pragma unroll
    for (int j = 0; j < 8; ++j) ld[j] = *(const float4*)(ap + j * 4);
    short* dst = &As[row * 264 + c0];
#pragma unroll
    for (int j = 0; j < 4; ++j)
      *(short8v*)(dst + j * 8) = pack8(ld[2 * j], ld[2 * j + 1]);
  }
  __syncthreads();

  f32x4 acc[2][4] = {};
  const short* wbase = Wp + (size_t)(wave * 64 + r) * 256;
#pragma unroll
  for (int ks = 0; ks < 8; ++ks) {
    short8v af0 = *(const short8v*)&As[r * 264 + ks * 32 + g * 8];
    short8v af1 = *(const short8v*)&As[(16 + r) * 264 + ks * 32 + g * 8];
    short8v bf[4];
#pragma unroll
    for (int nf = 0; nf < 4; ++nf)
      bf[nf] = *(const short8v*)(wbase + nf * 16 * 256 + ks * 32 + g * 8);
#pragma unroll
    for (int nf = 0; nf < 4; ++nf) {
      acc[0][nf] = __builtin_amdgcn_mfma_f32_16x16x32_bf16(af0, bf[nf], acc[0][nf], 0, 0, 0);
      acc[1][nf] = __builtin_amdgcn_mfma_f32_16x16x32_bf16(af1, bf[nf], acc[1][nf], 0, 0, 0);
    }
  }

#pragma unroll
  for (int mf = 0; mf < 2; ++mf)
#pragma unroll
    for (int nf = 0; nf < 4; ++nf) {
      int nn = wave * 64 + nf * 16 + r;
      float bval = bp[nn];
#pragma unroll
      for (int i = 0; i < 4; ++i) {
        int m = m0 + mf * 16 + g * 4 + i;
        float val = (acc[mf][nf][i] + bval) * scale;
        if (mode == 1) {
          int bb = m / 300, ll = m - bb * 300;
          Cf[((size_t)ll * 8 + bb) * 256 + nn] = val;
        } else {  // mode 3
          Cb[(size_t)m * 256 + nn] = (short)f2bf(val);
        }
      }
    }
}

// ---------------- value projection v3 (pipelined + clean stores) ----------------
// vvT[bn][d(32)][hw(9216)] bf16. grid 768 x 3 tiles of 32 rows (3 blocks/CU).
// Depth-2 register prefetch; per-wave LDS transpose epilogue (no extra barrier).
__global__ __launch_bounds__(256, 3) void vproj_kernel(
    const float* __restrict__ A, const short* __restrict__ Wb,
    const float* __restrict__ bias, short* __restrict__ vvT) {
  __shared__ short As[2][32 * 264];
  __shared__ short Ts[256 * 36];
  int t = threadIdx.x;
  int wave = t >> 6, lane = t & 63, r = lane & 15, g = lane >> 4;
  int row = t >> 3, c0 = (t & 7) * 32;
  int tile0 = blockIdx.x * 3;

  float bias_v[4];
#pragma unroll
  for (int nf = 0; nf < 4; ++nf) bias_v[nf] = bias[wave * 64 + nf * 16 + r];
  const short* wbase = Wb + (size_t)(wave * 64 + r) * 256;

  // prologue: issue loads for tiles 0 and 1 (both stay in flight)
  float4 ld0[8], ld1[8];
  {
    const float* ap = A + ((size_t)tile0 * 32 + row) * 256 + c0;
#pragma unroll
    for (int j = 0; j < 8; ++j) ld0[j] = *(const float4*)(ap + j * 4);
    ap += 32 * 256;
#pragma unroll
    for (int j = 0; j < 8; ++j) ld1[j] = *(const float4*)(ap + j * 4);
  }

#pragma unroll
  for (int tt = 0; tt < 3; ++tt) {
    // pack current tile into As[tt&1]
    {
      short* dst = &As[tt & 1][row * 264 + c0];
#pragma unroll
      for (int j = 0; j < 4; ++j)
        *(short8v*)(dst + j * 8) = pack8(ld0[2 * j], ld0[2 * j + 1]);
    }
    // rotate prefetch regs; issue tile tt+2 (stays in flight through MFMA)
#pragma unroll
    for (int j = 0; j < 8; ++j) ld0[j] = ld1[j];
    if (tt == 0) {
      const float* ap = A + ((size_t)(tile0 + 2) * 32 + row) * 256 + c0;
#pragma unroll
      for (int j = 0; j < 8; ++j) ld1[j] = *(const float4*)(ap + j * 4);
    }
    __syncthreads();

    f32x4 acc[2][4] = {};
    const short* as_ = &As[tt & 1][0];
#pragma unroll
    for (int ks = 0; ks < 8; ++ks) {
      short8v af0 = *(const short8v*)(as_ + r * 264 + ks * 32 + g * 8);
      short8v af1 = *(const short8v*)(as_ + (16 + r) * 264 + ks * 32 + g * 8);
      short8v bf[4];
#pragma unroll
      for (int nf = 0; nf < 4; ++nf)
        bf[nf] = *(const short8v*)(wbase + nf * 16 * 256 + ks * 32 + g * 8);
#pragma unroll
      for (int nf = 0; nf < 4; ++nf) {
        acc[0][nf] = __builtin_amdgcn_mfma_f32_16x16x32_bf16(af0, bf[nf], acc[0][nf], 0, 0, 0);
        acc[1][nf] = __builtin_amdgcn_mfma_f32_16x16x32_bf16(af1, bf[nf], acc[1][nf], 0, 0, 0);
      }
    }

    // per-wave transpose: channels wave*64..+63 are wave-local -> no barrier,
    // DS pipe is in-order per wave; fence stops compiler reordering.
#pragma unroll
    for (int nf = 0; nf < 4; ++nf) {
      int nn = wave * 64 + nf * 16 + r;
      float bval = bias_v[nf];
#pragma unroll
      for (int mf = 0; mf < 2; ++mf) {
        short4v o;
        o[0] = (short)f2bf(acc[mf][nf][0] + bval);
        o[1] = (short)f2bf(acc[mf][nf][1] + bval);
        o[2] = (short)f2bf(acc[mf][nf][2] + bval);
        o[3] = (short)f2bf(acc[mf][nf][3] + bval);
        *(short4v*)&Ts[nn * 36 + mf * 16 + g * 4] = o;
      }
    }
    asm volatile("" ::: "memory");
    int m0 = (tile0 + tt) * 32;
    int b_ = m0 / 9216, hw0 = m0 - b_ * 9216;
    short* gdst = vvT + (size_t)(b_ * 8 + (t >> 5)) * 294912 + (size_t)(t & 31) * 9216 + hw0;
#pragma unroll
    for (int j = 0; j < 4; ++j) {
      short4v lo = *(const short4v*)&Ts[t * 36 + j * 8];
      short4v hi = *(const short4v*)&Ts[t * 36 + j * 8 + 4];
      short8v v;
      v[0] = lo[0]; v[1] = lo[1]; v[2] = lo[2]; v[3] = lo[3];
      v[4] = hi[0]; v[5] = hi[1]; v[6] = hi[2]; v[7] = hi[3];
      *(short8v*)(gdst + j * 8) = v;
    }
    asm volatile("" ::: "memory");  // Ts reads complete before next iter's writes
  }
}

// ---------------- scores + softmax: MFMA + in-register softmax ----------------
__global__ __launch_bounds__(64) void scores_softmax_v2(
    const short* __restrict__ qrb, const short* __restrict__ qcb,
    const short* __restrict__ krb, const short* __restrict__ kcb,
    short* __restrict__ wrowB, float* __restrict__ wcolT) {
  int lchunk = blockIdx.x, bn = blockIdx.y, kind = blockIdx.z;
  int b = bn >> 3, n = bn & 7;
  int lane = threadIdx.x;
  int r = lane & 15, g = lane >> 4;
  const short* qb = kind ? qcb : qrb;
  const short* kb = kind ? kcb : krb;
  int l0 = lchunk * 80;

  short8v a[5], bfr[6];
#pragma unroll
  for (int lf = 0; lf < 5; ++lf) {
    int l = l0 + lf * 16 + r;
    if (l > 299) l = 299;
    a[lf] = *(const short8v*)(qb + ((size_t)b * 300 + l) * 256 + n * 32 + g * 8);
  }
#pragma unroll
  for (int f = 0; f < 6; ++f)
    bfr[f] = *(const short8v*)(kb + ((size_t)b * 96 + f * 16 + r) * 256 + n * 32 + g * 8);

  f32x4 c[5][6];
#pragma unroll
  for (int lf = 0; lf < 5; ++lf)
#pragma unroll
    for (int f = 0; f < 6; ++f) {
      f32x4 z = {};
      c[lf][f] = __builtin_amdgcn_mfma_f32_16x16x32_bf16(a[lf], bfr[f], z, 0, 0, 0);
    }

#pragma unroll
  for (int lf = 0; lf < 5; ++lf)
#pragma unroll
    for (int i = 0; i < 4; ++i) {
      float m = c[lf][0][i];
#pragma unroll
      for (int f = 1; f < 6; ++f) m = fmaxf(m, c[lf][f][i]);
#pragma unroll
      for (int mask = 1; mask <= 8; mask <<= 1) m = fmaxf(m, __shfl_xor(m, mask, 64));
      float e[6], s = 0.f;
#pragma unroll
      for (int f = 0; f < 6; ++f) { e[f] = __expf(c[lf][f][i] - m); s += e[f]; }
#pragma unroll
      for (int mask = 1; mask <= 8; mask <<= 1) s += __shfl_xor(s, mask, 64);
      float inv = 1.f / s;
#pragma unroll
      for (int f = 0; f < 6; ++f) c[lf][f][i] = e[f] * inv;
    }

  if (kind == 0) {
#pragma unroll
    for (int lf = 0; lf < 5; ++lf)
#pragma unroll
      for (int i = 0; i < 4; ++i) {
        int l = l0 + lf * 16 + g * 4 + i;
        bool ok = (l < 300);
#pragma unroll
        for (int f = 0; f < 6; ++f) {
          float wv = ok ? c[lf][f][i] : 0.f;
          wrowB[((size_t)bn * 320 + l) * 96 + f * 16 + r] = (short)f2bf(wv);
        }
      }
  } else {
#pragma unroll
    for (int lf = 0; lf < 5; ++lf)
#pragma unroll
      for (int f = 0; f < 6; ++f) {
        int l = l0 + lf * 16 + g * 4;
        f32x4 wv = c[lf][f];
#pragma unroll
        for (int i = 0; i < 4; ++i) if (l + i >= 300) wv[i] = 0.f;
        *(f32x4*)(wcolT + ((size_t)bn * 96 + f * 16 + r) * 320 + l) = wv;
      }
  }
}

// ---------------- fused bilinear attention (MFMA, 8 waves) ----------------
// grid (5,8,8); 8 waves: df = wave&1 (d half), hh = wave>>1 (h quarter, 24 each)
__global__ __launch_bounds__(512) void attn_kernel(
    const short* __restrict__ wrowB, const float* __restrict__ wcolT,
    const short* __restrict__ vvT, float* __restrict__ ao) {
  __shared__ f32x4 cmb[3][2][4][64];
  int lh = blockIdx.x, n = blockIdx.y, b = blockIdx.z;
  int bn = b * 8 + n;
  int t = threadIdx.x, wave = t >> 6, lane = t & 63;
  int df = wave & 1, hh = wave >> 1;
  int lbase = lh * 64;
  int r = lane & 15, g = lane >> 4;

  short8v a[4][3];
  const short* wr = wrowB + (size_t)bn * 320 * 96;
#pragma unroll
  for (int lf = 0; lf < 4; ++lf)
#pragma unroll
    for (int ks = 0; ks < 3; ++ks)
      a[lf][ks] = *(const short8v*)(wr + (lbase + lf * 16 + r) * 96 + ks * 32 + g * 8);

  const short* vb = vvT + (size_t)bn * 294912 + (size_t)(df * 16 + r) * 9216 + hh * 24 * 96;
  const float* wcb = wcolT + ((size_t)bn * 96 + hh * 24) * 320 + lbase + g * 4;

  f32x4 acc[4] = {};
  short8v b0[3], b1[3];
  f32x4 w0[4], w1[4];
#pragma unroll
  for (int ks = 0; ks < 3; ++ks) b0[ks] = *(const short8v*)(vb + ks * 32 + g * 8);
#pragma unroll
  for (int lf = 0; lf < 4; ++lf) w0[lf] = *(const f32x4*)(wcb + lf * 16);

  for (int h2 = 0; h2 < 12; ++h2) {
    int h = h2 * 2;
#pragma unroll
    for (int ks = 0; ks < 3; ++ks) b1[ks] = *(const short8v*)(vb + (h + 1) * 96 + ks * 32 + g * 8);
#pragma unroll
    for (int lf = 0; lf < 4; ++lf) w1[lf] = *(const f32x4*)(wcb + (h + 1) * 320 + lf * 16);
    {
      f32x4 R[4] = {};
#pragma unroll
      for (int ks = 0; ks < 3; ++ks)
#pragma unroll
        for (int lf = 0; lf < 4; ++lf)
          R[lf] = __builtin_amdgcn_mfma_f32_16x16x32_bf16(a[lf][ks], b0[ks], R[lf], 0, 0, 0);
#pragma unroll
      for (int lf = 0; lf < 4; ++lf) acc[lf] += w0[lf] * R[lf];
    }
    if (h2 < 11) {
#pragma unroll
      for (int ks = 0; ks < 3; ++ks) b0[ks] = *(const short8v*)(vb + (h + 2) * 96 + ks * 32 + g * 8);
#pragma unroll
      for (int lf = 0; lf < 4; ++lf) w0[lf] = *(const f32x4*)(wcb + (h + 2) * 320 + lf * 16);
    }
    {
      f32x4 R[4] = {};
#pragma unroll
      for (int ks = 0; ks < 3; ++ks)
#pragma unroll
        for (int lf = 0; lf < 4; ++lf)
          R[lf] = __builtin_amdgcn_mfma_f32_16x16x32_bf16(a[lf][ks], b1[ks], R[lf], 0, 0, 0);
#pragma unroll
      for (int lf = 0; lf < 4; ++lf) acc[lf] += w1[lf] * R[lf];
    }
  }

  if (hh > 0) {
#pragma unroll
    for (int lf = 0; lf < 4; ++lf) cmb[hh - 1][df][lf][lane] = acc[lf];
  }
  __syncthreads();
  if (hh == 0) {
#pragma unroll
    for (int lf = 0; lf < 4; ++lf) {
      f32x4 o = acc[lf];
#pragma unroll
      for (int q = 0; q < 3; ++q) o += cmb[q][df][lf][lane];
#pragma unroll
      for (int i = 0; i < 4; ++i) {
        int l = lbase + lf * 16 + g * 4 + i;
        if (l < 300)
          ao[((size_t)b * 300 + l) * 256 + n * 32 + df * 16 + r] = o[i];
      }
    }
  }
}

// ---------------- launch ----------------
extern "C" void kernel_launch(void* const* d_in, const int* in_sizes, int n_in,
                              void* d_out, int out_size, void* d_ws, size_t ws_size,
                              hipStream_t stream) {
  const float* query_row = (const float*)d_in[0];
  const float* query_col = (const float*)d_in[1];
  const float* key_row   = (const float*)d_in[2];
  const float* key_col   = (const float*)d_in[3];
  const float* value     = (const float*)d_in[4];
  const float* W         = (const float*)d_in[5];  // (1280,256)
  const float* Bv        = (const float*)d_in[6];  // (1280,)
  const float* Wout      = (const float*)d_in[7];  // (256,256)
  const float* Bout      = (const float*)d_in[8];  // (256,)

  float* ws = (float*)d_ws;
  float* krm   = ws;                        // 196608 f
  float* kcm   = krm + 196608;              // 196608 f
  float* ao    = kcm + 196608;              // 614400 f
  float* wcolT = ao + 614400;               // 1966080 f
  short* qrb   = (short*)(wcolT + 1966080); // 614400 s
  short* qcb   = qrb + 614400;              // 614400 s
  short* krb   = qcb + 614400;              // 196608 s
  short* kcb   = krb + 196608;              // 196608 s
  short* wrowB = kcb + 196608;              // 1966080 s
  short* vvT   = wrowB + 1966080;           // 18874368 s
  short* Wb    = vvT + 18874368;            // 393216 s

  cvt_w_kernel<<<1536, 256, 0, stream>>>(W, Wout, Wb);
  mean_over_h_v2<<<192, 256, 0, stream>>>(key_row, krm);
  mean_over_w_v2<<<192, 256, 0, stream>>>(key_col, kcm);
  gemm_proj<<<dim3(75, 2), 256, 0, stream>>>(query_row, query_col, Wb, Bv,
                                             nullptr, qrb, qcb, SCALE_Q, 3);
  gemm_proj<<<dim3(24, 2), 256, 0, stream>>>(krm, kcm, Wb + 131072, Bv + 512,
                                             nullptr, krb, kcb, 1.f, 3);
  vproj_kernel<<<768, 256, 0, stream>>>(value, Wb + 262144, Bv + 1024, vvT);
  scores_softmax_v2<<<dim3(4, 64, 2), 64, 0, stream>>>(qrb, qcb, krb, kcb, wrowB, wcolT);
  attn_kernel<<<dim3(5, 8, 8), 512, 0, stream>>>(wrowB, wcolT, vvT, ao);
  gemm_proj<<<dim3(75, 1), 256, 0, stream>>>(ao, nullptr, Wb + 327680, Bout,
                                             (float*)d_out, nullptr, nullptr, 1.f, 1);
}

// Round 7
// 170.996 us; speedup vs baseline: 7.5983x; 1.0500x over previous
//
#include <hip/hip_runtime.h>
#include <cstdint>

// MultiheadRCDA: N=8, L=300, HH=WW=96, E=256, NH=8, HD=32
// Round 7: vproj v5 — global_load_lds staging (deep vmcnt in-flight), B-frags
// hoisted to regs once/block, swizzled LDS, Ts epilogue. Means rebuilt for
// full-CU coverage.

typedef __attribute__((ext_vector_type(8))) short short8v;  // bf16x8 MFMA frag
typedef __attribute__((ext_vector_type(4))) short short4v;  // 8B packed bf16
typedef __attribute__((ext_vector_type(4))) float f32x4;

#define SCALE_Q 0.17677669529663687f  // 32^-0.5

#define GLL16(gp, lp)                                                   \
  __builtin_amdgcn_global_load_lds(                                     \
      (const __attribute__((address_space(1))) void*)(gp),              \
      (__attribute__((address_space(3))) void*)(lp), 16, 0, 0)

__device__ __forceinline__ unsigned short f2bf(float x) {
  unsigned int u = __builtin_bit_cast(unsigned int, x);
  u += 0x7FFFu + ((u >> 16) & 1u);
  return (unsigned short)(u >> 16);
}

__device__ __forceinline__ short8v pack8(const float4& fa, const float4& fb) {
  short8v v;
  v[0] = (short)f2bf(fa.x); v[1] = (short)f2bf(fa.y);
  v[2] = (short)f2bf(fa.z); v[3] = (short)f2bf(fa.w);
  v[4] = (short)f2bf(fb.x); v[5] = (short)f2bf(fb.y);
  v[6] = (short)f2bf(fb.z); v[7] = (short)f2bf(fb.w);
  return v;
}

__device__ __forceinline__ short8v pack8v(const f32x4& fa, const f32x4& fb) {
  short8v v;
  v[0] = (short)f2bf(fa[0]); v[1] = (short)f2bf(fa[1]);
  v[2] = (short)f2bf(fa[2]); v[3] = (short)f2bf(fa[3]);
  v[4] = (short)f2bf(fb[0]); v[5] = (short)f2bf(fb[1]);
  v[6] = (short)f2bf(fb[2]); v[7] = (short)f2bf(fb[3]);
  return v;
}

// ---------------- weight fp32->bf16 ----------------
__global__ __launch_bounds__(256) void cvt_w_kernel(const float* __restrict__ w_in,
                                                    const float* __restrict__ w_out,
                                                    short* __restrict__ Wb) {
  int idx = blockIdx.x * 256 + threadIdx.x;  // 393216 total
  float v = (idx < 327680) ? w_in[idx] : w_out[idx - 327680];
  Wb[idx] = (short)f2bf(v);
}

// ---------------- mean kernels v3: one block per output row, 4-way split ----
__global__ __launch_bounds__(256) void mean_over_h_v3(const float* __restrict__ in,
                                                      float* __restrict__ out) {
  __shared__ float4 part[256];
  int bw = blockIdx.x;  // b*96 + w
  int b = bw / 96, w = bw - b * 96;
  int t = threadIdx.x, e4 = t & 63, hq = t >> 6;
  const float4* p = (const float4*)(in + ((size_t)b * 9216 + w) * 256) + e4 +
                    (size_t)hq * 24 * 6144;
  float4 s = {0.f, 0.f, 0.f, 0.f};
#pragma unroll
  for (int i = 0; i < 24; ++i) {
    float4 v = p[(size_t)i * 6144];
    s.x += v.x; s.y += v.y; s.z += v.z; s.w += v.w;
  }
  part[t] = s;
  __syncthreads();
  if (t < 64) {
    float4 a = part[t], c = part[t + 64], d = part[t + 128], e = part[t + 192];
    float4 o;
    o.x = (a.x + c.x + d.x + e.x) * (1.f / 96.f);
    o.y = (a.y + c.y + d.y + e.y) * (1.f / 96.f);
    o.z = (a.z + c.z + d.z + e.z) * (1.f / 96.f);
    o.w = (a.w + c.w + d.w + e.w) * (1.f / 96.f);
    ((float4*)out)[(size_t)bw * 64 + t] = o;
  }
}

__global__ __launch_bounds__(256) void mean_over_w_v3(const float* __restrict__ in,
                                                      float* __restrict__ out) {
  __shared__ float4 part[256];
  int bh = blockIdx.x;  // b*96 + h
  int t = threadIdx.x, e4 = t & 63, wq = t >> 6;
  const float4* p = (const float4*)(in + (size_t)bh * 24576) + e4 + (size_t)wq * 24 * 64;
  float4 s = {0.f, 0.f, 0.f, 0.f};
#pragma unroll
  for (int i = 0; i < 24; ++i) {
    float4 v = p[(size_t)i * 64];
    s.x += v.x; s.y += v.y; s.z += v.z; s.w += v.w;
  }
  part[t] = s;
  __syncthreads();
  if (t < 64) {
    float4 a = part[t], c = part[t + 64], d = part[t + 128], e = part[t + 192];
    float4 o;
    o.x = (a.x + c.x + d.x + e.x) * (1.f / 96.f);
    o.y = (a.y + c.y + d.y + e.y) * (1.f / 96.f);
    o.z = (a.z + c.z + d.z + e.z) * (1.f / 96.f);
    o.w = (a.w + c.w + d.w + e.w) * (1.f / 96.f);
    ((float4*)out)[(size_t)bh * 64 + t] = o;
  }
}

// ---------------- bf16 MFMA projection GEMM (q/k/out), BM=32 ----------------
// C[M,256] = A[M,256] @ Wb[256,256]^T (+bias)*scale.  M % 32 == 0.
// blockIdx.y selects (A0,C0) vs (A1,C1) with W += y*65536, bias += y*256.
// mode 1: Cf[(l*8+b)][n] fp32 (m=b*300+l)   mode 3: Cb[m][256] bf16 (scaled)
__global__ __launch_bounds__(256) void gemm_proj(
    const float* __restrict__ A0, const float* __restrict__ A1,
    const short* __restrict__ Wb, const float* __restrict__ bias,
    float* __restrict__ Cf, short* __restrict__ Cb0, short* __restrict__ Cb1,
    float scale, int mode) {
  __shared__ short As[32 * 264];
  int y = blockIdx.y;
  const float* A = y ? A1 : A0;
  short* Cb = y ? Cb1 : Cb0;
  const short* Wp = Wb + y * 65536;
  const float* bp = bias + y * 256;
  int t = threadIdx.x;
  int m0 = blockIdx.x * 32;
  int wave = t >> 6, lane = t & 63, r = lane & 15, g = lane >> 4;

  {
    int row = t >> 3, c0 = (t & 7) * 32;
    const float* ap = A + ((size_t)m0 + row) * 256 + c0;
    float4 ld[8];
#pragma unroll
    for (int j = 0; j < 8; ++j) ld[j] = *(const float4*)(ap + j * 4);
    short* dst = &As[row * 264 + c0];
#pragma unroll
    for (int j = 0; j < 4; ++j)
      *(short8v*)(dst + j * 8) = pack8(ld[2 * j], ld[2 * j + 1]);
  }
  __syncthreads();

  f32x4 acc[2][4] = {};
  const short* wbase = Wp + (size_t)(wave * 64 + r) * 256;
#pragma unroll
  for (int ks = 0; ks < 8; ++ks) {
    short8v af0 = *(const short8v*)&As[r * 264 + ks * 32 + g * 8];
    short8v af1 = *(const short8v*)&As[(16 + r) * 264 + ks * 32 + g * 8];
    short8v bf[4];
#pragma unroll
    for (int nf = 0; nf < 4; ++nf)
      bf[nf] = *(const short8v*)(wbase + nf * 16 * 256 + ks * 32 + g * 8);
#pragma unroll
    for (int nf = 0; nf < 4; ++nf) {
      acc[0][nf] = __builtin_amdgcn_mfma_f32_16x16x32_bf16(af0, bf[nf], acc[0][nf], 0, 0, 0);
      acc[1][nf] = __builtin_amdgcn_mfma_f32_16x16x32_bf16(af1, bf[nf], acc[1][nf], 0, 0, 0);
    }
  }

#pragma unroll
  for (int mf = 0; mf < 2; ++mf)
#pragma unroll
    for (int nf = 0; nf < 4; ++nf) {
      int nn = wave * 64 + nf * 16 + r;
      float bval = bp[nn];
#pragma unroll
      for (int i = 0; i < 4; ++i) {
        int m = m0 + mf * 16 + g * 4 + i;
        float val = (acc[mf][nf][i] + bval) * scale;
        if (mode == 1) {
          int bb = m / 300, ll = m - bb * 300;
          Cf[((size_t)ll * 8 + bb) * 256 + nn] = val;
        } else {  // mode 3
          Cb[(size_t)m * 256 + nn] = (short)f2bf(val);
        }
      }
    }
}

// ---------------- value projection v5 (global_load_lds pipeline) ----------------
// vvT[bn][d(32)][hw(9216)] bf16. grid 576 x 8 tiles of 16 rows; 256 thr.
// A staged fp32 via GLL (dbuf 2x16KB), source-address XOR swizzle (16B granule);
// B-frags hoisted to 128 VGPRs once per block; Ts transpose epilogue per pair.
__global__ __launch_bounds__(256, 2) void vproj_kernel(
    const float* __restrict__ A, const short* __restrict__ Wb,
    const float* __restrict__ bias, short* __restrict__ vvT) {
  __shared__ float Asf[2][16][256];  // 32 KB
  __shared__ short Ts[256 * 36];     // 18.4 KB
  int t = threadIdx.x;
  int wave = t >> 6, lane = t & 63, r = lane & 15, g = lane >> 4;
  int tile0 = blockIdx.x * 8;

  // hoist B: wave's 64 n-cols, all of K. 32 frags = 128 VGPRs.
  short8v bf[8][4];
  const short* wbase = Wb + (size_t)(wave * 64 + r) * 256;
#pragma unroll
  for (int ks = 0; ks < 8; ++ks)
#pragma unroll
    for (int nf = 0; nf < 4; ++nf)
      bf[ks][nf] = *(const short8v*)(wbase + nf * 16 * 256 + ks * 32 + g * 8);

  float bias_v[4];
#pragma unroll
  for (int nf = 0; nf < 4; ++nf) bias_v[nf] = bias[wave * 64 + nf * 16 + r];

  // stage tile 0 (swizzled source, linear LDS dest)
  {
    const float* gsrc = A + (size_t)tile0 * 16 * 256;
#pragma unroll
    for (int i = 0; i < 4; ++i) {
      int row = wave * 4 + i;
      const float* gp = gsrc + row * 256 + ((lane ^ (row & 7)) << 2);
      GLL16(gp, &Asf[0][row][0]);
    }
  }
  __syncthreads();

  for (int tt = 0; tt < 8; ++tt) {
    int cur = tt & 1;
    if (tt < 7) {  // issue next tile's GLLs; they drain at the end-of-iter barrier
      const float* gsrc = A + (size_t)(tile0 + tt + 1) * 16 * 256;
#pragma unroll
      for (int i = 0; i < 4; ++i) {
        int row = wave * 4 + i;
        const float* gp = gsrc + row * 256 + ((lane ^ (row & 7)) << 2);
        GLL16(gp, &Asf[cur ^ 1][row][0]);
      }
    }

    // compute tile tt: frags read+converted from swizzled LDS
    f32x4 acc[4] = {};
    const float* base = &Asf[cur][r][0];
    int sw = r & 7;
#pragma unroll
    for (int ks = 0; ks < 8; ++ks) {
      int gr = ks * 8 + g * 2;
      f32x4 lo = *(const f32x4*)(base + ((gr ^ sw) << 2));
      f32x4 hi = *(const f32x4*)(base + (((gr + 1) ^ sw) << 2));
      short8v af = pack8v(lo, hi);
#pragma unroll
      for (int nf = 0; nf < 4; ++nf)
        acc[nf] = __builtin_amdgcn_mfma_f32_16x16x32_bf16(af, bf[ks][nf], acc[nf], 0, 0, 0);
    }

    // transpose to Ts (wave-local channels; tile parity selects 16-hw column)
#pragma unroll
    for (int nf = 0; nf < 4; ++nf) {
      int nn = wave * 64 + nf * 16 + r;
      float bv = bias_v[nf];
      short4v o;
      o[0] = (short)f2bf(acc[nf][0] + bv);
      o[1] = (short)f2bf(acc[nf][1] + bv);
      o[2] = (short)f2bf(acc[nf][2] + bv);
      o[3] = (short)f2bf(acc[nf][3] + bv);
      *(short4v*)&Ts[nn * 36 + cur * 16 + g * 4] = o;
    }
    asm volatile("" ::: "memory");
    if (tt & 1) {  // store the pair (tiles tt-1, tt): 64B per thread
      int m0 = (tile0 + tt - 1) * 16;
      int b_ = m0 / 9216, hw0 = m0 - b_ * 9216;
      short* gdst = vvT + (size_t)(b_ * 8 + (t >> 5)) * 294912 +
                    (size_t)(t & 31) * 9216 + hw0;
#pragma unroll
      for (int j = 0; j < 4; ++j) {
        short4v lo = *(const short4v*)&Ts[t * 36 + j * 8];
        short4v hi = *(const short4v*)&Ts[t * 36 + j * 8 + 4];
        short8v v;
        v[0] = lo[0]; v[1] = lo[1]; v[2] = lo[2]; v[3] = lo[3];
        v[4] = hi[0]; v[5] = hi[1]; v[6] = hi[2]; v[7] = hi[3];
        *(short8v*)(gdst + j * 8) = v;
      }
      asm volatile("" ::: "memory");
    }
    __syncthreads();  // drains GLLs for tile tt+1 and closes As/Ts reuse
  }
}

// ---------------- scores + softmax: MFMA + in-register softmax ----------------
__global__ __launch_bounds__(64) void scores_softmax_v2(
    const short* __restrict__ qrb, const short* __restrict__ qcb,
    const short* __restrict__ krb, const short* __restrict__ kcb,
    short* __restrict__ wrowB, float* __restrict__ wcolT) {
  int lchunk = blockIdx.x, bn = blockIdx.y, kind = blockIdx.z;
  int b = bn >> 3, n = bn & 7;
  int lane = threadIdx.x;
  int r = lane & 15, g = lane >> 4;
  const short* qb = kind ? qcb : qrb;
  const short* kb = kind ? kcb : krb;
  int l0 = lchunk * 80;

  short8v a[5], bfr[6];
#pragma unroll
  for (int lf = 0; lf < 5; ++lf) {
    int l = l0 + lf * 16 + r;
    if (l > 299) l = 299;
    a[lf] = *(const short8v*)(qb + ((size_t)b * 300 + l) * 256 + n * 32 + g * 8);
  }
#pragma unroll
  for (int f = 0; f < 6; ++f)
    bfr[f] = *(const short8v*)(kb + ((size_t)b * 96 + f * 16 + r) * 256 + n * 32 + g * 8);

  f32x4 c[5][6];
#pragma unroll
  for (int lf = 0; lf < 5; ++lf)
#pragma unroll
    for (int f = 0; f < 6; ++f) {
      f32x4 z = {};
      c[lf][f] = __builtin_amdgcn_mfma_f32_16x16x32_bf16(a[lf], bfr[f], z, 0, 0, 0);
    }

#pragma unroll
  for (int lf = 0; lf < 5; ++lf)
#pragma unroll
    for (int i = 0; i < 4; ++i) {
      float m = c[lf][0][i];
#pragma unroll
      for (int f = 1; f < 6; ++f) m = fmaxf(m, c[lf][f][i]);
#pragma unroll
      for (int mask = 1; mask <= 8; mask <<= 1) m = fmaxf(m, __shfl_xor(m, mask, 64));
      float e[6], s = 0.f;
#pragma unroll
      for (int f = 0; f < 6; ++f) { e[f] = __expf(c[lf][f][i] - m); s += e[f]; }
#pragma unroll
      for (int mask = 1; mask <= 8; mask <<= 1) s += __shfl_xor(s, mask, 64);
      float inv = 1.f / s;
#pragma unroll
      for (int f = 0; f < 6; ++f) c[lf][f][i] = e[f] * inv;
    }

  if (kind == 0) {
#pragma unroll
    for (int lf = 0; lf < 5; ++lf)
#pragma unroll
      for (int i = 0; i < 4; ++i) {
        int l = l0 + lf * 16 + g * 4 + i;
        bool ok = (l < 300);
#pragma unroll
        for (int f = 0; f < 6; ++f) {
          float wv = ok ? c[lf][f][i] : 0.f;
          wrowB[((size_t)bn * 320 + l) * 96 + f * 16 + r] = (short)f2bf(wv);
        }
      }
  } else {
#pragma unroll
    for (int lf = 0; lf < 5; ++lf)
#pragma unroll
      for (int f = 0; f < 6; ++f) {
        int l = l0 + lf * 16 + g * 4;
        f32x4 wv = c[lf][f];
#pragma unroll
        for (int i = 0; i < 4; ++i) if (l + i >= 300) wv[i] = 0.f;
        *(f32x4*)(wcolT + ((size_t)bn * 96 + f * 16 + r) * 320 + l) = wv;
      }
  }
}

// ---------------- fused bilinear attention (MFMA, 8 waves) ----------------
__global__ __launch_bounds__(512) void attn_kernel(
    const short* __restrict__ wrowB, const float* __restrict__ wcolT,
    const short* __restrict__ vvT, float* __restrict__ ao) {
  __shared__ f32x4 cmb[3][2][4][64];
  int lh = blockIdx.x, n = blockIdx.y, b = blockIdx.z;
  int bn = b * 8 + n;
  int t = threadIdx.x, wave = t >> 6, lane = t & 63;
  int df = wave & 1, hh = wave >> 1;
  int lbase = lh * 64;
  int r = lane & 15, g = lane >> 4;

  short8v a[4][3];
  const short* wr = wrowB + (size_t)bn * 320 * 96;
#pragma unroll
  for (int lf = 0; lf < 4; ++lf)
#pragma unroll
    for (int ks = 0; ks < 3; ++ks)
      a[lf][ks] = *(const short8v*)(wr + (lbase + lf * 16 + r) * 96 + ks * 32 + g * 8);

  const short* vb = vvT + (size_t)bn * 294912 + (size_t)(df * 16 + r) * 9216 + hh * 24 * 96;
  const float* wcb = wcolT + ((size_t)bn * 96 + hh * 24) * 320 + lbase + g * 4;

  f32x4 acc[4] = {};
  short8v b0[3], b1[3];
  f32x4 w0[4], w1[4];
#pragma unroll
  for (int ks = 0; ks < 3; ++ks) b0[ks] = *(const short8v*)(vb + ks * 32 + g * 8);
#pragma unroll
  for (int lf = 0; lf < 4; ++lf) w0[lf] = *(const f32x4*)(wcb + lf * 16);

  for (int h2 = 0; h2 < 12; ++h2) {
    int h = h2 * 2;
#pragma unroll
    for (int ks = 0; ks < 3; ++ks) b1[ks] = *(const short8v*)(vb + (h + 1) * 96 + ks * 32 + g * 8);
#pragma unroll
    for (int lf = 0; lf < 4; ++lf) w1[lf] = *(const f32x4*)(wcb + (h + 1) * 320 + lf * 16);
    {
      f32x4 R[4] = {};
#pragma unroll
      for (int ks = 0; ks < 3; ++ks)
#pragma unroll
        for (int lf = 0; lf < 4; ++lf)
          R[lf] = __builtin_amdgcn_mfma_f32_16x16x32_bf16(a[lf][ks], b0[ks], R[lf], 0, 0, 0);
#pragma unroll
      for (int lf = 0; lf < 4; ++lf) acc[lf] += w0[lf] * R[lf];
    }
    if (h2 < 11) {
#pragma unroll
      for (int ks = 0; ks < 3; ++ks) b0[ks] = *(const short8v*)(vb + (h + 2) * 96 + ks * 32 + g * 8);
#pragma unroll
      for (int lf = 0; lf < 4; ++lf) w0[lf] = *(const f32x4*)(wcb + (h + 2) * 320 + lf * 16);
    }
    {
      f32x4 R[4] = {};
#pragma unroll
      for (int ks = 0; ks < 3; ++ks)
#pragma unroll
        for (int lf = 0; lf < 4; ++lf)
          R[lf] = __builtin_amdgcn_mfma_f32_16x16x32_bf16(a[lf][ks], b1[ks], R[lf], 0, 0, 0);
#pragma unroll
      for (int lf = 0; lf < 4; ++lf) acc[lf] += w1[lf] * R[lf];
    }
  }

  if (hh > 0) {
#pragma unroll
    for (int lf = 0; lf < 4; ++lf) cmb[hh - 1][df][lf][lane] = acc[lf];
  }
  __syncthreads();
  if (hh == 0) {
#pragma unroll
    for (int lf = 0; lf < 4; ++lf) {
      f32x4 o = acc[lf];
#pragma unroll
      for (int q = 0; q < 3; ++q) o += cmb[q][df][lf][lane];
#pragma unroll
      for (int i = 0; i < 4; ++i) {
        int l = lbase + lf * 16 + g * 4 + i;
        if (l < 300)
          ao[((size_t)b * 300 + l) * 256 + n * 32 + df * 16 + r] = o[i];
      }
    }
  }
}

// ---------------- launch ----------------
extern "C" void kernel_launch(void* const* d_in, const int* in_sizes, int n_in,
                              void* d_out, int out_size, void* d_ws, size_t ws_size,
                              hipStream_t stream) {
  const float* query_row = (const float*)d_in[0];
  const float* query_col = (const float*)d_in[1];
  const float* key_row   = (const float*)d_in[2];
  const float* key_col   = (const float*)d_in[3];
  const float* value     = (const float*)d_in[4];
  const float* W         = (const float*)d_in[5];  // (1280,256)
  const float* Bv        = (const float*)d_in[6];  // (1280,)
  const float* Wout      = (const float*)d_in[7];  // (256,256)
  const float* Bout      = (const float*)d_in[8];  // (256,)

  float* ws = (float*)d_ws;
  float* krm   = ws;                        // 196608 f
  float* kcm   = krm + 196608;              // 196608 f
  float* ao    = kcm + 196608;              // 614400 f
  float* wcolT = ao + 614400;               // 1966080 f
  short* qrb   = (short*)(wcolT + 1966080); // 614400 s
  short* qcb   = qrb + 614400;              // 614400 s
  short* krb   = qcb + 614400;              // 196608 s
  short* kcb   = krb + 196608;              // 196608 s
  short* wrowB = kcb + 196608;              // 1966080 s
  short* vvT   = wrowB + 1966080;           // 18874368 s
  short* Wb    = vvT + 18874368;            // 393216 s

  cvt_w_kernel<<<1536, 256, 0, stream>>>(W, Wout, Wb);
  mean_over_h_v3<<<768, 256, 0, stream>>>(key_row, krm);
  mean_over_w_v3<<<768, 256, 0, stream>>>(key_col, kcm);
  gemm_proj<<<dim3(75, 2), 256, 0, stream>>>(query_row, query_col, Wb, Bv,
                                             nullptr, qrb, qcb, SCALE_Q, 3);
  gemm_proj<<<dim3(24, 2), 256, 0, stream>>>(krm, kcm, Wb + 131072, Bv + 512,
                                             nullptr, krb, kcb, 1.f, 3);
  vproj_kernel<<<576, 256, 0, stream>>>(value, Wb + 262144, Bv + 1024, vvT);
  scores_softmax_v2<<<dim3(4, 64, 2), 64, 0, stream>>>(qrb, qcb, krb, kcb, wrowB, wcolT);
  attn_kernel<<<dim3(5, 8, 8), 512, 0, stream>>>(wrowB, wcolT, vvT, ao);
  gemm_proj<<<dim3(75, 1), 256, 0, stream>>>(ao, nullptr, Wb + 327680, Bout,
                                             (float*)d_out, nullptr, nullptr, 1.f, 1);
}